// Round 9
// baseline (655.009 us; speedup 1.0000x reference)
//
#include <hip/hip_runtime.h>
#include <hip/hip_cooperative_groups.h>
#include <math.h>

namespace cg = cooperative_groups;

#define NNODES 40000
#define CCH    128
#define NH     8
#define HD     16
#define NEDGE  640000
#define FBLK   10000  // k_fused blocks (4 waves each -> 40000 nodes)
#define RBLK   40     // k_reduce_part blocks
#define CGRID  1024   // cooperative CSR grid

typedef __attribute__((ext_vector_type(8))) short bf16x8;
typedef __attribute__((ext_vector_type(4))) float f32x4;
typedef __attribute__((ext_vector_type(2))) float f32x2;

__device__ inline unsigned short f2bf(float f) {
  union { float f; unsigned u; } c; c.f = f;
  unsigned r = c.u + 0x7fffu + ((c.u >> 16) & 1u);
  return (unsigned short)(r >> 16);
}
__device__ inline float bfs(unsigned short u) { union { unsigned i; float f; } c; c.i = (unsigned)u << 16; return c.f; }
__device__ inline float bflo(unsigned u) { union { unsigned i; float f; } c; c.i = u << 16; return c.f; }
__device__ inline float bfhi(unsigned u) { union { unsigned i; float f; } c; c.i = u & 0xffff0000u; return c.f; }

// ---- fp8 e4m3 (OCP) helpers ----
__device__ inline unsigned char f2fp8(float v) {
#if __has_builtin(__builtin_amdgcn_cvt_pk_fp8_f32)
  return (unsigned char)(__builtin_amdgcn_cvt_pk_fp8_f32(v, v, 0, false) & 0xff);
#else
  union { float f; unsigned u; } c; c.f = v;
  unsigned s = (c.u >> 24) & 0x80;
  int e = (int)((c.u >> 23) & 0xff) - 127;
  unsigned m = c.u & 0x7fffff;
  if (e > 8) return s | 0x7e;
  if (e >= -6) {
    unsigned q = (m + 0x80000) >> 20; unsigned ee = e + 7;
    if (q == 8) { q = 0; ee++; }
    if (ee > 15) return s | 0x7e;
    return s | (ee << 3) | q;
  }
  if (e < -10) return (unsigned char)s;
  float a = fabsf(v); unsigned q = (unsigned)(a * 512.f + 0.5f); if (q > 7) q = 7;
  return s | q;
#endif
}
__device__ inline void fp8x4d(unsigned w, float* o) {
#if __has_builtin(__builtin_amdgcn_cvt_pk_f32_fp8)
  f32x2 lo = __builtin_amdgcn_cvt_pk_f32_fp8((int)w, false);
  f32x2 hi = __builtin_amdgcn_cvt_pk_f32_fp8((int)w, true);
  o[0] = lo[0]; o[1] = lo[1]; o[2] = hi[0]; o[3] = hi[1];
#else
  #pragma unroll
  for (int i = 0; i < 4; i++) {
    unsigned b = (w >> (8 * i)) & 0xff;
    unsigned s = b >> 7, e = (b >> 3) & 15, m = b & 7;
    float v;
    if (e) { union { unsigned u; float f; } c; c.u = ((e + 120) << 23) | (m << 20); v = c.f; }
    else v = m * (1.f / 512.f);
    o[i] = s ? -v : v;
  }
#endif
}

// ---------------- LayerNorm (LN1): 4 waves/block, 1 row/wave, bf16 out ----
__global__ __launch_bounds__(256) void k_ln_bf(const float* __restrict__ x,
                                               const float* __restrict__ g,
                                               const float* __restrict__ b,
                                               unsigned* __restrict__ out) {
  int wave = threadIdx.x >> 6;
  int lane = threadIdx.x & 63;
  int row  = blockIdx.x * 4 + wave;
  if (row >= NNODES) return;
  const float2* xr = (const float2*)(x + (size_t)row * CCH);
  float2 v = xr[lane];
  float s  = v.x + v.y;
  float ss = v.x * v.x + v.y * v.y;
  #pragma unroll
  for (int d = 1; d < 64; d <<= 1) {
    s  += __shfl_xor(s, d);
    ss += __shfl_xor(ss, d);
  }
  float mean = s * (1.0f / CCH);
  float var  = ss * (1.0f / CCH) - mean * mean;
  float rstd = rsqrtf(var + 1e-5f);
  float2 gg = ((const float2*)g)[lane];
  float2 bb = ((const float2*)b)[lane];
  float ox = (v.x - mean) * rstd * gg.x + bb.x;
  float oy = (v.y - mean) * rstd * gg.y + bb.y;
  out[(size_t)row * 64 + lane] = ((unsigned)f2bf(oy) << 16) | f2bf(ox);
}

// -------- Combined weight prep: Wq|Wk|Wv -> Wqkvt, W1t, W2t, bqkv ---------
__global__ __launch_bounds__(256) void k_wprep_all(const float* __restrict__ Wq,
                                                   const float* __restrict__ Wk,
                                                   const float* __restrict__ Wv,
                                                   const float* __restrict__ W1,
                                                   const float* __restrict__ W2,
                                                   const float* __restrict__ bq,
                                                   const float* __restrict__ bk,
                                                   const float* __restrict__ bv,
                                                   unsigned short* __restrict__ Wqkvt,
                                                   unsigned short* __restrict__ W1t,
                                                   unsigned short* __restrict__ W2t,
                                                   float* __restrict__ bqkv) {
  int idx = blockIdx.x * 256 + threadIdx.x;
  if (idx < 16384) { int n = idx >> 7, k = idx & 127; Wqkvt[idx] = f2bf(Wq[(size_t)k * 128 + n]); return; }
  idx -= 16384;
  if (idx < 16384) { int n = idx >> 7, k = idx & 127; Wqkvt[16384 + (n << 7) + k] = f2bf(Wk[(size_t)k * 128 + n]); return; }
  idx -= 16384;
  if (idx < 16384) { int n = idx >> 7, k = idx & 127; Wqkvt[32768 + (n << 7) + k] = f2bf(Wv[(size_t)k * 128 + n]); return; }
  idx -= 16384;
  if (idx < 65536) { int n = idx >> 7, k = idx & 127; W1t[idx] = f2bf(W1[(size_t)k * 512 + n]); return; }
  idx -= 65536;
  if (idx < 65536) { int n = idx >> 9, k = idx & 511; W2t[idx] = f2bf(W2[(size_t)k * 128 + n]); return; }
  idx -= 65536;
  if (idx < 384) bqkv[idx] = idx < 128 ? bq[idx] : (idx < 256 ? bk[idx - 128] : bv[idx - 256]);
}

// -------- Wo prep: inline inv computation from dpart + row scaling --------
__global__ __launch_bounds__(256) void k_wprep_wo(const float* __restrict__ W,
                                                  const float* __restrict__ dpart,
                                                  unsigned short* __restrict__ Wt) {
  __shared__ float sinv[8];
  if (threadIdx.x < 64) {
    int h = threadIdx.x & 7;
    float s = 0.f;
    for (int r = threadIdx.x >> 3; r < RBLK; r += 8) s += dpart[r * 8 + h];
    #pragma unroll
    for (int d = 8; d < 64; d <<= 1) s += __shfl_xor(s, d);
    if (threadIdx.x < 8) sinv[h] = 1.0f / s;
  }
  __syncthreads();
  int idx = blockIdx.x * 256 + threadIdx.x;
  if (idx >= CCH * CCH) return;
  int n = idx >> 7, k = idx & 127;
  Wt[idx] = f2bf(W[(size_t)k * CCH + n] * sinv[k >> 4]);
}

// ------ MFMA GEMM.
// MODE: 0=f32 out, 1=bf16 out, 2=qkv-packed (512B rows),
//       3=Wo+LN2 fused (outp=x1 bf16, outp2=xn2 bf16, res fp32 required)
// RESMODE: 0=none, 1=fp32, 2=bf16
template <bool RELU, int RESMODE, int MODE>
__global__ __launch_bounds__(256) void k_mgemm(const unsigned short* __restrict__ A,
                                               const unsigned short* __restrict__ Bt,
                                               const float* __restrict__ bias,
                                               const void* __restrict__ res,
                                               void* __restrict__ outp,
                                               int K, int Nc,
                                               const float* __restrict__ lng,
                                               const float* __restrict__ lnb,
                                               void* __restrict__ outp2) {
  __shared__ unsigned short As[64 * 64];
  __shared__ unsigned short Bs[128 * 64];
  const int tid  = threadIdx.x;
  const int row0 = blockIdx.x * 64;
  const int c0   = blockIdx.y * 128;
  const int l    = tid & 63;
  const int w    = tid >> 6;
  const int wr   = w >> 1;
  const int wc   = w & 1;

  f32x4 acc[2][4] = {};

  for (int kc = 0; kc < K; kc += 64) {
    __syncthreads();
    #pragma unroll
    for (int it = 0; it < 2; it++) {
      int idx = it * 256 + tid;
      int r = idx >> 3, s = idx & 7;
      uint4 vv = *(const uint4*)(A + (size_t)(row0 + r) * K + kc + s * 8);
      *(uint4*)(As + r * 64 + ((s ^ (r & 7)) * 8)) = vv;
    }
    #pragma unroll
    for (int it = 0; it < 4; it++) {
      int idx = it * 256 + tid;
      int n = idx >> 3, s = idx & 7;
      uint4 vv = *(const uint4*)(Bt + (size_t)(c0 + n) * K + kc + s * 8);
      *(uint4*)(Bs + n * 64 + ((s ^ (n & 7)) * 8)) = vv;
    }
    __syncthreads();
    #pragma unroll
    for (int kk = 0; kk < 2; kk++) {
      int sb = kk * 4 + (l >> 4);
      bf16x8 af[2], bfr[4];
      #pragma unroll
      for (int mi = 0; mi < 2; mi++) {
        int r = wr * 32 + mi * 16 + (l & 15);
        af[mi] = *(const bf16x8*)(As + r * 64 + ((sb ^ (r & 7)) * 8));
      }
      #pragma unroll
      for (int ni = 0; ni < 4; ni++) {
        int n = wc * 64 + ni * 16 + (l & 15);
        bfr[ni] = *(const bf16x8*)(Bs + n * 64 + ((sb ^ (n & 7)) * 8));
      }
      #pragma unroll
      for (int mi = 0; mi < 2; mi++)
        #pragma unroll
        for (int ni = 0; ni < 4; ni++)
          acc[mi][ni] = __builtin_amdgcn_mfma_f32_16x16x32_bf16(af[mi], bfr[ni], acc[mi][ni], 0, 0, 0);
    }
  }

  if constexpr (MODE == 3) {
    // Wo + residual + LN2 fusion. Nc==128, one col-tile per block (c0==0).
    __shared__ float lnS[64][2], lnSS[64][2], gS[128], bS[128];
    if (tid < 128) { gS[tid] = lng[tid]; bS[tid] = lnb[tid]; }
    #pragma unroll
    for (int mi = 0; mi < 2; mi++) {
      #pragma unroll
      for (int p = 0; p < 4; p++) {
        int lr = wr * 32 + mi * 16 + (l >> 4) * 4 + p;
        int r  = row0 + lr;
        float s = 0.f, ss = 0.f;
        #pragma unroll
        for (int ni = 0; ni < 4; ni++) {
          int c = wc * 64 + ni * 16 + (l & 15);
          float val = acc[mi][ni][p] + bias[c] + ((const float*)res)[(size_t)r * 128 + c];
          acc[mi][ni][p] = val;
          s += val; ss += val * val;
        }
        #pragma unroll
        for (int d = 1; d < 16; d <<= 1) { s += __shfl_xor(s, d); ss += __shfl_xor(ss, d); }
        if ((l & 15) == 0) { lnS[lr][wc] = s; lnSS[lr][wc] = ss; }
      }
    }
    __syncthreads();
    #pragma unroll
    for (int mi = 0; mi < 2; mi++) {
      #pragma unroll
      for (int p = 0; p < 4; p++) {
        int lr = wr * 32 + mi * 16 + (l >> 4) * 4 + p;
        int r  = row0 + lr;
        float m   = (lnS[lr][0] + lnS[lr][1]) * (1.f / 128.f);
        float var = (lnSS[lr][0] + lnSS[lr][1]) * (1.f / 128.f) - m * m;
        float rstd = rsqrtf(var + 1e-5f);
        #pragma unroll
        for (int ni = 0; ni < 4; ni++) {
          int c = wc * 64 + ni * 16 + (l & 15);
          float val = acc[mi][ni][p];
          ((unsigned short*)outp)[(size_t)r * 128 + c]  = f2bf(val);
          ((unsigned short*)outp2)[(size_t)r * 128 + c] = f2bf((val - m) * rstd * gS[c] + bS[c]);
        }
      }
    }
  } else {
    #pragma unroll
    for (int mi = 0; mi < 2; mi++) {
      #pragma unroll
      for (int p = 0; p < 4; p++) {
        int r = row0 + wr * 32 + mi * 16 + (l >> 4) * 4 + p;
        #pragma unroll
        for (int ni = 0; ni < 4; ni++) {
          int c = c0 + wc * 64 + ni * 16 + (l & 15);
          float val = acc[mi][ni][p] + bias[c];
          if (RESMODE == 1) val += ((const float*)res)[(size_t)r * Nc + c];
          if (RESMODE == 2) val += bfs(((const unsigned short*)res)[(size_t)r * Nc + c]);
          if (RELU) val = fmaxf(val, 0.f);
          if (MODE == 0)      ((float*)outp)[(size_t)r * Nc + c] = val;
          else if (MODE == 1) ((unsigned short*)outp)[(size_t)r * Nc + c] = f2bf(val);
          else {
            char* rowb = (char*)outp + (size_t)r * 512;
            if (c < 128) *(unsigned short*)(rowb + c * 2) = f2bf(val);
            else         *(unsigned char*)(rowb + 256 + (c - 128)) = f2fp8(val);
          }
        }
      }
    }
  }
}

// ------- Cooperative CSR build: zero -> histrank -> scan -> scatter -------
__global__ __launch_bounds__(256) void k_csr(const int* __restrict__ ei,
                                             int* __restrict__ deg,
                                             int* __restrict__ rank,
                                             int* __restrict__ off,
                                             int* __restrict__ bsum,
                                             int* __restrict__ srcs) {
  cg::grid_group grid = cg::this_grid();
  const int tid = threadIdx.x;
  const int gid = blockIdx.x * 256 + tid;
  const int GSZ = CGRID * 256;
  __shared__ int ws4[4];

  for (int i = gid; i < NNODES; i += GSZ) deg[i] = 0;
  grid.sync();

  for (int e = gid; e < NEDGE; e += GSZ)
    rank[e] = atomicAdd(&deg[ei[NEDGE + e]], 1);
  grid.sync();

  {  // per-block degree sums
    int d = (gid < NNODES) ? deg[gid] : 0;
    #pragma unroll
    for (int s = 1; s < 64; s <<= 1) d += __shfl_xor(d, s);
    if ((tid & 63) == 0) ws4[tid >> 6] = d;
    __syncthreads();
    if (tid == 0) bsum[blockIdx.x] = ws4[0] + ws4[1] + ws4[2] + ws4[3];
  }
  grid.sync();

  if (blockIdx.x == 0) {  // exclusive scan of bsum[1024] in place
    int v0 = bsum[4 * tid], v1 = bsum[4 * tid + 1], v2 = bsum[4 * tid + 2], v3 = bsum[4 * tid + 3];
    int ls = v0 + v1 + v2 + v3;
    int lane = tid & 63, wv = tid >> 6;
    int incl = ls;
    #pragma unroll
    for (int s = 1; s < 64; s <<= 1) { int o = __shfl_up(incl, s); if (lane >= s) incl += o; }
    __syncthreads();
    if (lane == 63) ws4[wv] = incl;
    __syncthreads();
    int base = 0;
    for (int w2 = 0; w2 < wv; w2++) base += ws4[w2];
    int ex = base + incl - ls;
    bsum[4 * tid] = ex; bsum[4 * tid + 1] = ex + v0;
    bsum[4 * tid + 2] = ex + v0 + v1; bsum[4 * tid + 3] = ex + v0 + v1 + v2;
  }
  grid.sync();

  {  // block-local scan + block prefix -> off
    int d = (gid < NNODES) ? deg[gid] : 0;
    int lane = tid & 63, wv = tid >> 6;
    int incl = d;
    #pragma unroll
    for (int s = 1; s < 64; s <<= 1) { int o = __shfl_up(incl, s); if (lane >= s) incl += o; }
    __syncthreads();
    if (lane == 63) ws4[wv] = incl;
    __syncthreads();
    int base = bsum[blockIdx.x];
    for (int w2 = 0; w2 < wv; w2++) base += ws4[w2];
    int ex = base + incl - d;
    if (gid < NNODES) off[gid] = ex;
    if (gid == 0) off[NNODES] = NEDGE;
  }
  grid.sync();

  for (int e = gid; e < NEDGE; e += GSZ)
    srcs[off[ei[NEDGE + e]] + rank[e]] = ei[e];
}

// ------- Fused scores + aggregation: 1 wave/node, 1 lane = 1 (edge,head) ---
// qkv row (512B): [0,256) q bf16 x128; [256,384) k fp8 x128; [384,512) v fp8.
__global__ __launch_bounds__(256) void k_fused(const unsigned char* __restrict__ qkv,
                                               const int* __restrict__ off,
                                               const int* __restrict__ srcs,
                                               unsigned* __restrict__ U,
                                               float* __restrict__ hpart) {
  const int wave = threadIdx.x >> 6;
  const int lane = threadIdx.x & 63;
  const int n  = blockIdx.x * 4 + wave;
  const int g  = lane >> 3;   // edge slot 0..7
  const int c8 = lane & 7;    // head; channels c8*16 .. +15

  const uint4* qp = (const uint4*)(qkv + (size_t)n * 512 + c8 * 32);
  uint4 qa = qp[0], qb = qp[1];
  float qf[16];
  qf[0]=bflo(qa.x);  qf[1]=bfhi(qa.x);  qf[2]=bflo(qa.y);  qf[3]=bfhi(qa.y);
  qf[4]=bflo(qa.z);  qf[5]=bfhi(qa.z);  qf[6]=bflo(qa.w);  qf[7]=bfhi(qa.w);
  qf[8]=bflo(qb.x);  qf[9]=bfhi(qb.x);  qf[10]=bflo(qb.y); qf[11]=bfhi(qb.y);
  qf[12]=bflo(qb.z); qf[13]=bfhi(qb.z); qf[14]=bflo(qb.w); qf[15]=bfhi(qb.w);

  float acc[16];
  #pragma unroll
  for (int i = 0; i < 16; i++) acc[i] = 0.f;
  float lsum = 0.f;

  const int i0 = off[n], i1 = off[n + 1];
  for (int jb = i0; jb < i1; jb += 8) {
    int j = jb + g;
    bool valid = j < i1;
    int src = srcs[valid ? j : jb];
    const uint4* kp = (const uint4*)(qkv + (size_t)src * 512 + 256 + c8 * 16);
    uint4 kw = kp[0];
    uint4 vw = kp[8];      // +128 B -> v row
    float kf[16], vf[16];
    fp8x4d(kw.x, kf + 0); fp8x4d(kw.y, kf + 4); fp8x4d(kw.z, kf + 8); fp8x4d(kw.w, kf + 12);
    fp8x4d(vw.x, vf + 0); fp8x4d(vw.y, vf + 4); fp8x4d(vw.z, vf + 8); fp8x4d(vw.w, vf + 12);
    float p = 0.f;
    #pragma unroll
    for (int i = 0; i < 16; i++) p += qf[i] * kf[i];
    float w = valid ? __expf(p * 0.25f) : 0.f;
    lsum += w;
    #pragma unroll
    for (int i = 0; i < 16; i++) acc[i] += w * vf[i];
  }

  #pragma unroll
  for (int d = 8; d < 64; d <<= 1) {
    #pragma unroll
    for (int i = 0; i < 16; i++) acc[i] += __shfl_xor(acc[i], d);
    lsum += __shfl_xor(lsum, d);
  }

  __shared__ float wsum[4][8];
  if (lane < 8) {
    wsum[wave][c8] = lsum;
    unsigned o[8];
    #pragma unroll
    for (int i = 0; i < 8; i++)
      o[i] = ((unsigned)f2bf(acc[2 * i + 1]) << 16) | f2bf(acc[2 * i]);
    uint4* up = (uint4*)(U + (size_t)n * 64 + c8 * 8);
    up[0] = make_uint4(o[0], o[1], o[2], o[3]);
    up[1] = make_uint4(o[4], o[5], o[6], o[7]);
  }
  __syncthreads();
  if (threadIdx.x < 8) {
    hpart[blockIdx.x * 8 + threadIdx.x] =
        wsum[0][threadIdx.x] + wsum[1][threadIdx.x] + wsum[2][threadIdx.x] + wsum[3][threadIdx.x];
  }
}

// ---- Stage-1 denominator reduce: hpart[10000][8] -> dpart[40][8] ----------
__global__ __launch_bounds__(256) void k_reduce_part(const float* __restrict__ hpart,
                                                     float* __restrict__ dpart) {
  const int t = threadIdx.x;
  const int h = t & 7;
  const int r0 = blockIdx.x * (FBLK / RBLK);
  float s = 0.f;
  for (int r = r0 + (t >> 3); r < r0 + FBLK / RBLK; r += 32) s += hpart[r * 8 + h];
  #pragma unroll
  for (int d = 8; d < 64; d <<= 1) s += __shfl_xor(s, d);
  __shared__ float ws4[4][8];
  int lane = t & 63, wv = t >> 6;
  if (lane < 8) ws4[wv][lane] = s;
  __syncthreads();
  if (t < 8) dpart[blockIdx.x * 8 + t] = ws4[0][t] + ws4[1][t] + ws4[2][t] + ws4[3][t];
}

extern "C" void kernel_launch(void* const* d_in, const int* in_sizes, int n_in,
                              void* d_out, int out_size, void* d_ws, size_t ws_size,
                              hipStream_t stream) {
  const float* x    = (const float*)d_in[0];
  const int*   ei   = (const int*)d_in[1];
  const float* Wq   = (const float*)d_in[2];
  const float* bq   = (const float*)d_in[3];
  const float* Wk   = (const float*)d_in[4];
  const float* bk   = (const float*)d_in[5];
  const float* Wv   = (const float*)d_in[6];
  const float* bv   = (const float*)d_in[7];
  const float* Wo   = (const float*)d_in[8];
  const float* bo   = (const float*)d_in[9];
  const float* ln1g = (const float*)d_in[10];
  const float* ln1b = (const float*)d_in[11];
  const float* ln2g = (const float*)d_in[12];
  const float* ln2b = (const float*)d_in[13];
  const float* W1   = (const float*)d_in[14];
  const float* b1   = (const float*)d_in[15];
  const float* W2   = (const float*)d_in[16];
  const float* b2   = (const float*)d_in[17];
  float* out = (float*)d_out;

  char* p = (char*)d_ws;
  const size_t NCb = (size_t)NNODES * CCH * 2;                  // 10.24 MB
  unsigned short* xn   = (unsigned short*)p; p += NCb;          // xn / xn2
  unsigned char*  qkvb = (unsigned char*)p;  p += (size_t)NNODES * 512;  // 20.48 MB (ffn1 start)
  unsigned short* agg  = (unsigned short*)p; p += NCb;          // U (ffn1 part)
  p += NCb;                                                     // spare (ffn1 part)
  unsigned short* x1b  = (unsigned short*)p; p += NCb;          // x1 bf16
  int* deg    = (int*)p;                     p += (size_t)NNODES * 4 + 256;
  int* off    = (int*)p;                     p += (size_t)(NNODES + 1) * 4 + 256;
  int* rank   = (int*)p;                     p += (size_t)NEDGE * 4;
  int* srcs   = (int*)p;                     p += (size_t)NEDGE * 4;
  int* bsum   = (int*)p;                     p += (size_t)CGRID * 4 + 256;
  float* hpart = (float*)p;                  p += (size_t)FBLK * 8 * 4;
  float* dpart = (float*)p;                  p += (size_t)RBLK * 8 * 4 + 256;
  float* bqkv  = (float*)p;                  p += 384 * 4 + 256;
  unsigned short* Wqkvt = (unsigned short*)p; p += (size_t)384 * CCH * 2;
  unsigned short* Wot   = (unsigned short*)p; p += (size_t)CCH * CCH * 2;
  unsigned short* W1t   = (unsigned short*)p; p += (size_t)CCH * 4 * CCH * 2;
  unsigned short* W2t   = (unsigned short*)p; p += (size_t)CCH * 4 * CCH * 2;
  unsigned short* ffn1 = (unsigned short*)qkvb;  // overlays qkvb+agg+spare (40.96 MB)
  unsigned short* xn2  = xn;

  dim3 blk(256);
  dim3 gLN(NNODES / 4);
  dim3 gM(NNODES / 64, 1);
  dim3 gM3(NNODES / 64, 3);
  dim3 gM4(NNODES / 64, 4);

  // 1. CSR build — one cooperative kernel (zero/hist+rank/scan/scatter)
  {
    const int* eip = ei;
    int *degp = deg, *rankp = rank, *offp = off, *bsump = bsum, *srcsp = srcs;
    void* args[] = {(void*)&eip, (void*)&degp, (void*)&rankp,
                    (void*)&offp, (void*)&bsump, (void*)&srcsp};
    hipLaunchCooperativeKernel((void*)k_csr, dim3(CGRID), blk, args, 0, stream);
  }

  // 2. all weight prep in one launch
  k_wprep_all<<<706, blk, 0, stream>>>(Wq, Wk, Wv, W1, W2, bq, bk, bv,
                                       Wqkvt, W1t, W2t, bqkv);

  // 3-4. LN1 + packed QKV GEMM (q bf16 | k fp8 | v fp8, 512B rows)
  k_ln_bf<<<gLN, blk, 0, stream>>>(x, ln1g, ln1b, (unsigned*)xn);
  k_mgemm<false, 0, 2><<<gM3, blk, 0, stream>>>(xn, Wqkvt, bqkv, nullptr, qkvb,
                                                CCH, 384, nullptr, nullptr, nullptr);

  // 5-6. fused scores+aggregation, denominator partials
  k_fused<<<FBLK, blk, 0, stream>>>(qkvb, off, srcs, (unsigned*)agg, hpart);
  k_reduce_part<<<RBLK, blk, 0, stream>>>(hpart, dpart);

  // 7. Wo prep (inv inline) -> 8. Wo GEMM + residual-x + LN2 fused
  k_wprep_wo<<<64, blk, 0, stream>>>(Wo, dpart, Wot);
  k_mgemm<false, 1, 3><<<gM, blk, 0, stream>>>(agg, Wot, bo, x, x1b,
                                               CCH, CCH, ln2g, ln2b, xn2);

  // 9. FFN1 (relu, bf16 out)
  k_mgemm<true, 0, 1><<<gM4, blk, 0, stream>>>(xn2, W1t, b1, nullptr, ffn1,
                                               CCH, 4 * CCH, nullptr, nullptr, nullptr);
  // 10. FFN2 (+bf16 residual x1) -> d_out fp32
  k_mgemm<false, 2, 0><<<gM, blk, 0, stream>>>(ffn1, W2t, b2, x1b, out,
                                               4 * CCH, CCH, nullptr, nullptr, nullptr);
}

// Round 10
// 167.478 us; speedup vs baseline: 3.9110x; 3.9110x over previous
//
#include <hip/hip_runtime.h>
#include <math.h>

#define NNODES 40000
#define CCH    128
#define NH     8
#define HD     16
#define NEDGE  640000
#define NBLK   157    // ceil(NNODES/256)
#define FBLK   10000  // k_fused blocks (4 waves each -> 40000 nodes)
#define RBLK   40     // k_reduce_part blocks

typedef __attribute__((ext_vector_type(8))) short bf16x8;
typedef __attribute__((ext_vector_type(4))) float f32x4;
typedef __attribute__((ext_vector_type(2))) float f32x2;

__device__ inline unsigned short f2bf(float f) {
  union { float f; unsigned u; } c; c.f = f;
  unsigned r = c.u + 0x7fffu + ((c.u >> 16) & 1u);
  return (unsigned short)(r >> 16);
}
__device__ inline float bfs(unsigned short u) { union { unsigned i; float f; } c; c.i = (unsigned)u << 16; return c.f; }
__device__ inline float bflo(unsigned u) { union { unsigned i; float f; } c; c.i = u << 16; return c.f; }
__device__ inline float bfhi(unsigned u) { union { unsigned i; float f; } c; c.i = u & 0xffff0000u; return c.f; }

// ---- fp8 e4m3 (OCP) helpers ----
__device__ inline unsigned char f2fp8(float v) {
#if __has_builtin(__builtin_amdgcn_cvt_pk_fp8_f32)
  return (unsigned char)(__builtin_amdgcn_cvt_pk_fp8_f32(v, v, 0, false) & 0xff);
#else
  union { float f; unsigned u; } c; c.f = v;
  unsigned s = (c.u >> 24) & 0x80;
  int e = (int)((c.u >> 23) & 0xff) - 127;
  unsigned m = c.u & 0x7fffff;
  if (e > 8) return s | 0x7e;
  if (e >= -6) {
    unsigned q = (m + 0x80000) >> 20; unsigned ee = e + 7;
    if (q == 8) { q = 0; ee++; }
    if (ee > 15) return s | 0x7e;
    return s | (ee << 3) | q;
  }
  if (e < -10) return (unsigned char)s;
  float a = fabsf(v); unsigned q = (unsigned)(a * 512.f + 0.5f); if (q > 7) q = 7;
  return s | q;
#endif
}
__device__ inline void fp8x4d(unsigned w, float* o) {
#if __has_builtin(__builtin_amdgcn_cvt_pk_f32_fp8)
  f32x2 lo = __builtin_amdgcn_cvt_pk_f32_fp8((int)w, false);
  f32x2 hi = __builtin_amdgcn_cvt_pk_f32_fp8((int)w, true);
  o[0] = lo[0]; o[1] = lo[1]; o[2] = hi[0]; o[3] = hi[1];
#else
  #pragma unroll
  for (int i = 0; i < 4; i++) {
    unsigned b = (w >> (8 * i)) & 0xff;
    unsigned s = b >> 7, e = (b >> 3) & 15, m = b & 7;
    float v;
    if (e) { union { unsigned u; float f; } c; c.u = ((e + 120) << 23) | (m << 20); v = c.f; }
    else v = m * (1.f / 512.f);
    o[i] = s ? -v : v;
  }
#endif
}

// ---------------- LayerNorm (LN1): 4 waves/block, 1 row/wave, bf16 out ----
__global__ __launch_bounds__(256) void k_ln_bf(const float* __restrict__ x,
                                               const float* __restrict__ g,
                                               const float* __restrict__ b,
                                               unsigned* __restrict__ out) {
  int wave = threadIdx.x >> 6;
  int lane = threadIdx.x & 63;
  int row  = blockIdx.x * 4 + wave;
  if (row >= NNODES) return;
  const float2* xr = (const float2*)(x + (size_t)row * CCH);
  float2 v = xr[lane];
  float s  = v.x + v.y;
  float ss = v.x * v.x + v.y * v.y;
  #pragma unroll
  for (int d = 1; d < 64; d <<= 1) {
    s  += __shfl_xor(s, d);
    ss += __shfl_xor(ss, d);
  }
  float mean = s * (1.0f / CCH);
  float var  = ss * (1.0f / CCH) - mean * mean;
  float rstd = rsqrtf(var + 1e-5f);
  float2 gg = ((const float2*)g)[lane];
  float2 bb = ((const float2*)b)[lane];
  float ox = (v.x - mean) * rstd * gg.x + bb.x;
  float oy = (v.y - mean) * rstd * gg.y + bb.y;
  out[(size_t)row * 64 + lane] = ((unsigned)f2bf(oy) << 16) | f2bf(ox);
}

// -------- Combined weight prep: Wq|Wk|Wv -> Wqkvt, W1t, W2t, bqkv ---------
__global__ __launch_bounds__(256) void k_wprep_all(const float* __restrict__ Wq,
                                                   const float* __restrict__ Wk,
                                                   const float* __restrict__ Wv,
                                                   const float* __restrict__ W1,
                                                   const float* __restrict__ W2,
                                                   const float* __restrict__ bq,
                                                   const float* __restrict__ bk,
                                                   const float* __restrict__ bv,
                                                   unsigned short* __restrict__ Wqkvt,
                                                   unsigned short* __restrict__ W1t,
                                                   unsigned short* __restrict__ W2t,
                                                   float* __restrict__ bqkv) {
  int idx = blockIdx.x * 256 + threadIdx.x;
  if (idx < 16384) { int n = idx >> 7, k = idx & 127; Wqkvt[idx] = f2bf(Wq[(size_t)k * 128 + n]); return; }
  idx -= 16384;
  if (idx < 16384) { int n = idx >> 7, k = idx & 127; Wqkvt[16384 + (n << 7) + k] = f2bf(Wk[(size_t)k * 128 + n]); return; }
  idx -= 16384;
  if (idx < 16384) { int n = idx >> 7, k = idx & 127; Wqkvt[32768 + (n << 7) + k] = f2bf(Wv[(size_t)k * 128 + n]); return; }
  idx -= 16384;
  if (idx < 65536) { int n = idx >> 7, k = idx & 127; W1t[idx] = f2bf(W1[(size_t)k * 512 + n]); return; }
  idx -= 65536;
  if (idx < 65536) { int n = idx >> 9, k = idx & 511; W2t[idx] = f2bf(W2[(size_t)k * 128 + n]); return; }
  idx -= 65536;
  if (idx < 384) bqkv[idx] = idx < 128 ? bq[idx] : (idx < 256 ? bk[idx - 128] : bv[idx - 256]);
}

// -------- Wo prep: inline inv computation from dpart + row scaling --------
__global__ __launch_bounds__(256) void k_wprep_wo(const float* __restrict__ W,
                                                  const float* __restrict__ dpart,
                                                  unsigned short* __restrict__ Wt) {
  __shared__ float sinv[8];
  if (threadIdx.x < 64) {
    int h = threadIdx.x & 7;
    float s = 0.f;
    for (int r = threadIdx.x >> 3; r < RBLK; r += 8) s += dpart[r * 8 + h];
    #pragma unroll
    for (int d = 8; d < 64; d <<= 1) s += __shfl_xor(s, d);
    if (threadIdx.x < 8) sinv[h] = 1.0f / s;
  }
  __syncthreads();
  int idx = blockIdx.x * 256 + threadIdx.x;
  if (idx >= CCH * CCH) return;
  int n = idx >> 7, k = idx & 127;
  Wt[idx] = f2bf(W[(size_t)k * CCH + n] * sinv[k >> 4]);
}

// ------ MFMA GEMM.
// MODE: 0=f32 out, 1=bf16 out, 2=qkv-packed (512B rows),
//       3=Wo+LN2 fused (outp=x1 bf16, outp2=xn2 bf16, res fp32 required)
// RESMODE: 0=none, 1=fp32, 2=bf16
template <bool RELU, int RESMODE, int MODE>
__global__ __launch_bounds__(256) void k_mgemm(const unsigned short* __restrict__ A,
                                               const unsigned short* __restrict__ Bt,
                                               const float* __restrict__ bias,
                                               const void* __restrict__ res,
                                               void* __restrict__ outp,
                                               int K, int Nc,
                                               const float* __restrict__ lng,
                                               const float* __restrict__ lnb,
                                               void* __restrict__ outp2) {
  __shared__ unsigned short As[64 * 64];
  __shared__ unsigned short Bs[128 * 64];
  const int tid  = threadIdx.x;
  const int row0 = blockIdx.x * 64;
  const int c0   = blockIdx.y * 128;
  const int l    = tid & 63;
  const int w    = tid >> 6;
  const int wr   = w >> 1;
  const int wc   = w & 1;

  f32x4 acc[2][4] = {};

  for (int kc = 0; kc < K; kc += 64) {
    __syncthreads();
    #pragma unroll
    for (int it = 0; it < 2; it++) {
      int idx = it * 256 + tid;
      int r = idx >> 3, s = idx & 7;
      uint4 vv = *(const uint4*)(A + (size_t)(row0 + r) * K + kc + s * 8);
      *(uint4*)(As + r * 64 + ((s ^ (r & 7)) * 8)) = vv;
    }
    #pragma unroll
    for (int it = 0; it < 4; it++) {
      int idx = it * 256 + tid;
      int n = idx >> 3, s = idx & 7;
      uint4 vv = *(const uint4*)(Bt + (size_t)(c0 + n) * K + kc + s * 8);
      *(uint4*)(Bs + n * 64 + ((s ^ (n & 7)) * 8)) = vv;
    }
    __syncthreads();
    #pragma unroll
    for (int kk = 0; kk < 2; kk++) {
      int sb = kk * 4 + (l >> 4);
      bf16x8 af[2], bfr[4];
      #pragma unroll
      for (int mi = 0; mi < 2; mi++) {
        int r = wr * 32 + mi * 16 + (l & 15);
        af[mi] = *(const bf16x8*)(As + r * 64 + ((sb ^ (r & 7)) * 8));
      }
      #pragma unroll
      for (int ni = 0; ni < 4; ni++) {
        int n = wc * 64 + ni * 16 + (l & 15);
        bfr[ni] = *(const bf16x8*)(Bs + n * 64 + ((sb ^ (n & 7)) * 8));
      }
      #pragma unroll
      for (int mi = 0; mi < 2; mi++)
        #pragma unroll
        for (int ni = 0; ni < 4; ni++)
          acc[mi][ni] = __builtin_amdgcn_mfma_f32_16x16x32_bf16(af[mi], bfr[ni], acc[mi][ni], 0, 0, 0);
    }
  }

  if constexpr (MODE == 3) {
    // Wo + residual + LN2 fusion. Nc==128, one col-tile per block (c0==0).
    __shared__ float lnS[64][2], lnSS[64][2], gS[128], bS[128];
    if (tid < 128) { gS[tid] = lng[tid]; bS[tid] = lnb[tid]; }
    #pragma unroll
    for (int mi = 0; mi < 2; mi++) {
      #pragma unroll
      for (int p = 0; p < 4; p++) {
        int lr = wr * 32 + mi * 16 + (l >> 4) * 4 + p;
        int r  = row0 + lr;
        float s = 0.f, ss = 0.f;
        #pragma unroll
        for (int ni = 0; ni < 4; ni++) {
          int c = wc * 64 + ni * 16 + (l & 15);
          float val = acc[mi][ni][p] + bias[c] + ((const float*)res)[(size_t)r * 128 + c];
          acc[mi][ni][p] = val;
          s += val; ss += val * val;
        }
        #pragma unroll
        for (int d = 1; d < 16; d <<= 1) { s += __shfl_xor(s, d); ss += __shfl_xor(ss, d); }
        if ((l & 15) == 0) { lnS[lr][wc] = s; lnSS[lr][wc] = ss; }
      }
    }
    __syncthreads();
    #pragma unroll
    for (int mi = 0; mi < 2; mi++) {
      #pragma unroll
      for (int p = 0; p < 4; p++) {
        int lr = wr * 32 + mi * 16 + (l >> 4) * 4 + p;
        int r  = row0 + lr;
        float m   = (lnS[lr][0] + lnS[lr][1]) * (1.f / 128.f);
        float var = (lnSS[lr][0] + lnSS[lr][1]) * (1.f / 128.f) - m * m;
        float rstd = rsqrtf(var + 1e-5f);
        #pragma unroll
        for (int ni = 0; ni < 4; ni++) {
          int c = wc * 64 + ni * 16 + (l & 15);
          float val = acc[mi][ni][p];
          ((unsigned short*)outp)[(size_t)r * 128 + c]  = f2bf(val);
          ((unsigned short*)outp2)[(size_t)r * 128 + c] = f2bf((val - m) * rstd * gS[c] + bS[c]);
        }
      }
    }
  } else {
    #pragma unroll
    for (int mi = 0; mi < 2; mi++) {
      #pragma unroll
      for (int p = 0; p < 4; p++) {
        int r = row0 + wr * 32 + mi * 16 + (l >> 4) * 4 + p;
        #pragma unroll
        for (int ni = 0; ni < 4; ni++) {
          int c = c0 + wc * 64 + ni * 16 + (l & 15);
          float val = acc[mi][ni][p] + bias[c];
          if (RESMODE == 1) val += ((const float*)res)[(size_t)r * Nc + c];
          if (RESMODE == 2) val += bfs(((const unsigned short*)res)[(size_t)r * Nc + c]);
          if (RELU) val = fmaxf(val, 0.f);
          if (MODE == 0)      ((float*)outp)[(size_t)r * Nc + c] = val;
          else if (MODE == 1) ((unsigned short*)outp)[(size_t)r * Nc + c] = f2bf(val);
          else {
            char* rowb = (char*)outp + (size_t)r * 512;
            if (c < 128) *(unsigned short*)(rowb + c * 2) = f2bf(val);
            else         *(unsigned char*)(rowb + 256 + (c - 128)) = f2fp8(val);
          }
        }
      }
    }
  }
}

// ------- CSR build: histogram+rank -> 3-stage scan -> atomic-free scatter --
__global__ __launch_bounds__(256) void k_histrank(const int* __restrict__ ei,
                                                  int* __restrict__ deg,
                                                  int* __restrict__ rank) {
  int e = blockIdx.x * 256 + threadIdx.x;
  if (e >= NEDGE) return;
  rank[e] = atomicAdd(&deg[ei[NEDGE + e]], 1);
}

__global__ __launch_bounds__(256) void k_scan3a(const int* __restrict__ deg,
                                                int* __restrict__ bsum) {
  int i = blockIdx.x * 256 + threadIdx.x;
  int d = (i < NNODES) ? deg[i] : 0;
  #pragma unroll
  for (int s = 1; s < 64; s <<= 1) d += __shfl_xor(d, s);
  __shared__ int ws4[4];
  if ((threadIdx.x & 63) == 0) ws4[threadIdx.x >> 6] = d;
  __syncthreads();
  if (threadIdx.x == 0) bsum[blockIdx.x] = ws4[0] + ws4[1] + ws4[2] + ws4[3];
}

__global__ __launch_bounds__(256) void k_scan3b(const int* __restrict__ bsum,
                                                int* __restrict__ bpre) {
  int t = threadIdx.x;
  int d = (t < NBLK) ? bsum[t] : 0;
  int lane = t & 63, wv = t >> 6;
  int incl = d;
  #pragma unroll
  for (int s = 1; s < 64; s <<= 1) { int o = __shfl_up(incl, s); if (lane >= s) incl += o; }
  __shared__ int wsum[4];
  if (lane == 63) wsum[wv] = incl;
  __syncthreads();
  int base = 0;
  for (int w2 = 0; w2 < wv; w2++) base += wsum[w2];
  if (t < NBLK) bpre[t] = base + incl - d;
}

__global__ __launch_bounds__(256) void k_scan3c(const int* __restrict__ deg,
                                                const int* __restrict__ bpre,
                                                int* __restrict__ off) {
  int t = threadIdx.x;
  int i = blockIdx.x * 256 + t;
  int d = (i < NNODES) ? deg[i] : 0;
  int lane = t & 63, wv = t >> 6;
  int incl = d;
  #pragma unroll
  for (int s = 1; s < 64; s <<= 1) { int o = __shfl_up(incl, s); if (lane >= s) incl += o; }
  __shared__ int wsum[4];
  if (lane == 63) wsum[wv] = incl;
  __syncthreads();
  int base = bpre[blockIdx.x];
  for (int w2 = 0; w2 < wv; w2++) base += wsum[w2];
  int ex = base + incl - d;
  if (i < NNODES) off[i] = ex;
  if (i == 0) off[NNODES] = NEDGE;
}

__global__ __launch_bounds__(256) void k_scatter(const int* __restrict__ ei,
                                                 const int* __restrict__ off,
                                                 const int* __restrict__ rank,
                                                 int* __restrict__ srcs) {
  int e = blockIdx.x * 256 + threadIdx.x;
  if (e >= NEDGE) return;
  srcs[off[ei[NEDGE + e]] + rank[e]] = ei[e];
}

// ------- Fused scores + aggregation: 1 wave/node, 1 lane = 1 (edge,head) ---
// qkv row (512B): [0,256) q bf16 x128; [256,384) k fp8 x128; [384,512) v fp8.
__global__ __launch_bounds__(256) void k_fused(const unsigned char* __restrict__ qkv,
                                               const int* __restrict__ off,
                                               const int* __restrict__ srcs,
                                               unsigned* __restrict__ U,
                                               float* __restrict__ hpart) {
  const int wave = threadIdx.x >> 6;
  const int lane = threadIdx.x & 63;
  const int n  = blockIdx.x * 4 + wave;
  const int g  = lane >> 3;   // edge slot 0..7
  const int c8 = lane & 7;    // head; channels c8*16 .. +15

  const uint4* qp = (const uint4*)(qkv + (size_t)n * 512 + c8 * 32);
  uint4 qa = qp[0], qb = qp[1];
  float qf[16];
  qf[0]=bflo(qa.x);  qf[1]=bfhi(qa.x);  qf[2]=bflo(qa.y);  qf[3]=bfhi(qa.y);
  qf[4]=bflo(qa.z);  qf[5]=bfhi(qa.z);  qf[6]=bflo(qa.w);  qf[7]=bfhi(qa.w);
  qf[8]=bflo(qb.x);  qf[9]=bfhi(qb.x);  qf[10]=bflo(qb.y); qf[11]=bfhi(qb.y);
  qf[12]=bflo(qb.z); qf[13]=bfhi(qb.z); qf[14]=bflo(qb.w); qf[15]=bfhi(qb.w);

  float acc[16];
  #pragma unroll
  for (int i = 0; i < 16; i++) acc[i] = 0.f;
  float lsum = 0.f;

  const int i0 = off[n], i1 = off[n + 1];
  for (int jb = i0; jb < i1; jb += 8) {
    int j = jb + g;
    bool valid = j < i1;
    int src = srcs[valid ? j : jb];
    const uint4* kp = (const uint4*)(qkv + (size_t)src * 512 + 256 + c8 * 16);
    uint4 kw = kp[0];
    uint4 vw = kp[8];      // +128 B -> v row
    float kf[16], vf[16];
    fp8x4d(kw.x, kf + 0); fp8x4d(kw.y, kf + 4); fp8x4d(kw.z, kf + 8); fp8x4d(kw.w, kf + 12);
    fp8x4d(vw.x, vf + 0); fp8x4d(vw.y, vf + 4); fp8x4d(vw.z, vf + 8); fp8x4d(vw.w, vf + 12);
    float p = 0.f;
    #pragma unroll
    for (int i = 0; i < 16; i++) p += qf[i] * kf[i];
    float w = valid ? __expf(p * 0.25f) : 0.f;
    lsum += w;
    #pragma unroll
    for (int i = 0; i < 16; i++) acc[i] += w * vf[i];
  }

  #pragma unroll
  for (int d = 8; d < 64; d <<= 1) {
    #pragma unroll
    for (int i = 0; i < 16; i++) acc[i] += __shfl_xor(acc[i], d);
    lsum += __shfl_xor(lsum, d);
  }

  __shared__ float wsum[4][8];
  if (lane < 8) {
    wsum[wave][c8] = lsum;
    unsigned o[8];
    #pragma unroll
    for (int i = 0; i < 8; i++)
      o[i] = ((unsigned)f2bf(acc[2 * i + 1]) << 16) | f2bf(acc[2 * i]);
    uint4* up = (uint4*)(U + (size_t)n * 64 + c8 * 8);
    up[0] = make_uint4(o[0], o[1], o[2], o[3]);
    up[1] = make_uint4(o[4], o[5], o[6], o[7]);
  }
  __syncthreads();
  if (threadIdx.x < 8) {
    hpart[blockIdx.x * 8 + threadIdx.x] =
        wsum[0][threadIdx.x] + wsum[1][threadIdx.x] + wsum[2][threadIdx.x] + wsum[3][threadIdx.x];
  }
}

// ---- Stage-1 denominator reduce: hpart[10000][8] -> dpart[40][8] ----------
__global__ __launch_bounds__(256) void k_reduce_part(const float* __restrict__ hpart,
                                                     float* __restrict__ dpart) {
  const int t = threadIdx.x;
  const int h = t & 7;
  const int r0 = blockIdx.x * (FBLK / RBLK);
  float s = 0.f;
  for (int r = r0 + (t >> 3); r < r0 + FBLK / RBLK; r += 32) s += hpart[r * 8 + h];
  #pragma unroll
  for (int d = 8; d < 64; d <<= 1) s += __shfl_xor(s, d);
  __shared__ float ws4[4][8];
  int lane = t & 63, wv = t >> 6;
  if (lane < 8) ws4[wv][lane] = s;
  __syncthreads();
  if (t < 8) dpart[blockIdx.x * 8 + t] = ws4[0][t] + ws4[1][t] + ws4[2][t] + ws4[3][t];
}

extern "C" void kernel_launch(void* const* d_in, const int* in_sizes, int n_in,
                              void* d_out, int out_size, void* d_ws, size_t ws_size,
                              hipStream_t stream) {
  const float* x    = (const float*)d_in[0];
  const int*   ei   = (const int*)d_in[1];
  const float* Wq   = (const float*)d_in[2];
  const float* bq   = (const float*)d_in[3];
  const float* Wk   = (const float*)d_in[4];
  const float* bk   = (const float*)d_in[5];
  const float* Wv   = (const float*)d_in[6];
  const float* bv   = (const float*)d_in[7];
  const float* Wo   = (const float*)d_in[8];
  const float* bo   = (const float*)d_in[9];
  const float* ln1g = (const float*)d_in[10];
  const float* ln1b = (const float*)d_in[11];
  const float* ln2g = (const float*)d_in[12];
  const float* ln2b = (const float*)d_in[13];
  const float* W1   = (const float*)d_in[14];
  const float* b1   = (const float*)d_in[15];
  const float* W2   = (const float*)d_in[16];
  const float* b2   = (const float*)d_in[17];
  float* out = (float*)d_out;

  char* p = (char*)d_ws;
  const size_t NCb = (size_t)NNODES * CCH * 2;                  // 10.24 MB
  unsigned short* xn   = (unsigned short*)p; p += NCb;          // xn / xn2
  unsigned char*  qkvb = (unsigned char*)p;  p += (size_t)NNODES * 512;  // 20.48 MB (ffn1 start)
  unsigned short* agg  = (unsigned short*)p; p += NCb;          // U (ffn1 part)
  p += NCb;                                                     // spare (ffn1 part)
  unsigned short* x1b  = (unsigned short*)p; p += NCb;          // x1 bf16
  int* deg    = (int*)p;                     p += (size_t)NNODES * 4 + 256;
  int* off    = (int*)p;                     p += (size_t)(NNODES + 1) * 4 + 256;
  int* rank   = (int*)p;                     p += (size_t)NEDGE * 4;
  int* srcs   = (int*)p;                     p += (size_t)NEDGE * 4;
  int* bsum   = (int*)p;                     p += 256 * 4;
  int* bpre   = (int*)p;                     p += 256 * 4;
  float* hpart = (float*)p;                  p += (size_t)FBLK * 8 * 4;
  float* dpart = (float*)p;                  p += (size_t)RBLK * 8 * 4 + 256;
  float* bqkv  = (float*)p;                  p += 384 * 4 + 256;
  unsigned short* Wqkvt = (unsigned short*)p; p += (size_t)384 * CCH * 2;
  unsigned short* Wot   = (unsigned short*)p; p += (size_t)CCH * CCH * 2;
  unsigned short* W1t   = (unsigned short*)p; p += (size_t)CCH * 4 * CCH * 2;
  unsigned short* W2t   = (unsigned short*)p; p += (size_t)CCH * 4 * CCH * 2;
  unsigned short* ffn1 = (unsigned short*)qkvb;  // overlays qkvb+agg+spare (40.96 MB)
  unsigned short* xn2  = xn;

  dim3 blk(256);
  dim3 gLN(NNODES / 4);
  dim3 gM(NNODES / 64, 1);
  dim3 gM3(NNODES / 64, 3);
  dim3 gM4(NNODES / 64, 4);
  dim3 gE((NEDGE + 255) / 256);

  // CSR build: memset + hist+rank -> 3-stage scan -> atomic-free scatter
  hipMemsetAsync(deg, 0, (size_t)NNODES * 4, stream);
  k_histrank<<<gE, blk, 0, stream>>>(ei, deg, rank);
  k_scan3a<<<NBLK, blk, 0, stream>>>(deg, bsum);
  k_scan3b<<<1, blk, 0, stream>>>(bsum, bpre);
  k_scan3c<<<NBLK, blk, 0, stream>>>(deg, bpre, off);
  k_scatter<<<gE, blk, 0, stream>>>(ei, off, rank, srcs);

  // all weight prep in one launch
  k_wprep_all<<<706, blk, 0, stream>>>(Wq, Wk, Wv, W1, W2, bq, bk, bv,
                                       Wqkvt, W1t, W2t, bqkv);

  // LN1 + packed QKV GEMM (q bf16 | k fp8 | v fp8, 512B rows)
  k_ln_bf<<<gLN, blk, 0, stream>>>(x, ln1g, ln1b, (unsigned*)xn);
  k_mgemm<false, 0, 2><<<gM3, blk, 0, stream>>>(xn, Wqkvt, bqkv, nullptr, qkvb,
                                                CCH, 384, nullptr, nullptr, nullptr);

  // fused scores+aggregation, denominator partials
  k_fused<<<FBLK, blk, 0, stream>>>(qkvb, off, srcs, (unsigned*)agg, hpart);
  k_reduce_part<<<RBLK, blk, 0, stream>>>(hpart, dpart);

  // Wo prep (inv inline) -> Wo GEMM + residual-x + LN2 fused
  k_wprep_wo<<<64, blk, 0, stream>>>(Wo, dpart, Wot);
  k_mgemm<false, 1, 3><<<gM, blk, 0, stream>>>(agg, Wot, bo, x, x1b,
                                               CCH, CCH, ln2g, ln2b, xn2);

  // FFN1 (relu, bf16 out)
  k_mgemm<true, 0, 1><<<gM4, blk, 0, stream>>>(xn2, W1t, b1, nullptr, ffn1,
                                               CCH, 4 * CCH, nullptr, nullptr, nullptr);
  // FFN2 (+bf16 residual x1) -> d_out fp32
  k_mgemm<false, 2, 0><<<gM, blk, 0, stream>>>(ffn1, W2t, b2, x1b, out,
                                               4 * CCH, CCH, nullptr, nullptr, nullptr);
}

// Round 11
// 161.408 us; speedup vs baseline: 4.0581x; 1.0376x over previous
//
#include <hip/hip_runtime.h>
#include <math.h>

#define NNODES 40000
#define CCH    128
#define NH     8
#define HD     16
#define NEDGE  640000
#define NBLK   157    // ceil(NNODES/256)
#define FBLK   10000  // k_fused blocks (4 waves each -> 40000 nodes)
#define RBLK   40     // k_reduce_part blocks

typedef __attribute__((ext_vector_type(8))) short bf16x8;
typedef __attribute__((ext_vector_type(4))) float f32x4;
typedef __attribute__((ext_vector_type(2))) float f32x2;

__device__ inline unsigned short f2bf(float f) {
  union { float f; unsigned u; } c; c.f = f;
  unsigned r = c.u + 0x7fffu + ((c.u >> 16) & 1u);
  return (unsigned short)(r >> 16);
}
__device__ inline float bfs(unsigned short u) { union { unsigned i; float f; } c; c.i = (unsigned)u << 16; return c.f; }
__device__ inline float bflo(unsigned u) { union { unsigned i; float f; } c; c.i = u << 16; return c.f; }
__device__ inline float bfhi(unsigned u) { union { unsigned i; float f; } c; c.i = u & 0xffff0000u; return c.f; }

// ---- fp8 e4m3 (OCP) helpers ----
__device__ inline unsigned char f2fp8(float v) {
#if __has_builtin(__builtin_amdgcn_cvt_pk_fp8_f32)
  return (unsigned char)(__builtin_amdgcn_cvt_pk_fp8_f32(v, v, 0, false) & 0xff);
#else
  union { float f; unsigned u; } c; c.f = v;
  unsigned s = (c.u >> 24) & 0x80;
  int e = (int)((c.u >> 23) & 0xff) - 127;
  unsigned m = c.u & 0x7fffff;
  if (e > 8) return s | 0x7e;
  if (e >= -6) {
    unsigned q = (m + 0x80000) >> 20; unsigned ee = e + 7;
    if (q == 8) { q = 0; ee++; }
    if (ee > 15) return s | 0x7e;
    return s | (ee << 3) | q;
  }
  if (e < -10) return (unsigned char)s;
  float a = fabsf(v); unsigned q = (unsigned)(a * 512.f + 0.5f); if (q > 7) q = 7;
  return s | q;
#endif
}
__device__ inline void fp8x4d(unsigned w, float* o) {
#if __has_builtin(__builtin_amdgcn_cvt_pk_f32_fp8)
  f32x2 lo = __builtin_amdgcn_cvt_pk_f32_fp8((int)w, false);
  f32x2 hi = __builtin_amdgcn_cvt_pk_f32_fp8((int)w, true);
  o[0] = lo[0]; o[1] = lo[1]; o[2] = hi[0]; o[3] = hi[1];
#else
  #pragma unroll
  for (int i = 0; i < 4; i++) {
    unsigned b = (w >> (8 * i)) & 0xff;
    unsigned s = b >> 7, e = (b >> 3) & 15, m = b & 7;
    float v;
    if (e) { union { unsigned u; float f; } c; c.u = ((e + 120) << 23) | (m << 20); v = c.f; }
    else v = m * (1.f / 512.f);
    o[i] = s ? -v : v;
  }
#endif
}

// -------- Combined weight prep (+deg zeroing): Wqkvt, W1t, W2t, bqkv ------
__global__ __launch_bounds__(256) void k_wprep_all(const float* __restrict__ Wq,
                                                   const float* __restrict__ Wk,
                                                   const float* __restrict__ Wv,
                                                   const float* __restrict__ W1,
                                                   const float* __restrict__ W2,
                                                   const float* __restrict__ bq,
                                                   const float* __restrict__ bk,
                                                   const float* __restrict__ bv,
                                                   unsigned short* __restrict__ Wqkvt,
                                                   unsigned short* __restrict__ W1t,
                                                   unsigned short* __restrict__ W2t,
                                                   float* __restrict__ bqkv,
                                                   int* __restrict__ deg) {
  int g0 = blockIdx.x * 256 + threadIdx.x;
  if (g0 < NNODES) deg[g0] = 0;
  int idx = g0;
  if (idx < 16384) { int n = idx >> 7, k = idx & 127; Wqkvt[idx] = f2bf(Wq[(size_t)k * 128 + n]); return; }
  idx -= 16384;
  if (idx < 16384) { int n = idx >> 7, k = idx & 127; Wqkvt[16384 + (n << 7) + k] = f2bf(Wk[(size_t)k * 128 + n]); return; }
  idx -= 16384;
  if (idx < 16384) { int n = idx >> 7, k = idx & 127; Wqkvt[32768 + (n << 7) + k] = f2bf(Wv[(size_t)k * 128 + n]); return; }
  idx -= 16384;
  if (idx < 65536) { int n = idx >> 7, k = idx & 127; W1t[idx] = f2bf(W1[(size_t)k * 512 + n]); return; }
  idx -= 65536;
  if (idx < 65536) { int n = idx >> 9, k = idx & 511; W2t[idx] = f2bf(W2[(size_t)k * 128 + n]); return; }
  idx -= 65536;
  if (idx < 384) bqkv[idx] = idx < 128 ? bq[idx] : (idx < 256 ? bk[idx - 128] : bv[idx - 256]);
}

// -------- Wo prep: inline inv computation from dpart + row scaling --------
__global__ __launch_bounds__(256) void k_wprep_wo(const float* __restrict__ W,
                                                  const float* __restrict__ dpart,
                                                  unsigned short* __restrict__ Wt) {
  __shared__ float sinv[8];
  if (threadIdx.x < 64) {
    int h = threadIdx.x & 7;
    float s = 0.f;
    for (int r = threadIdx.x >> 3; r < RBLK; r += 8) s += dpart[r * 8 + h];
    #pragma unroll
    for (int d = 8; d < 64; d <<= 1) s += __shfl_xor(s, d);
    if (threadIdx.x < 8) sinv[h] = 1.0f / s;
  }
  __syncthreads();
  int idx = blockIdx.x * 256 + threadIdx.x;
  if (idx >= CCH * CCH) return;
  int n = idx >> 7, k = idx & 127;
  Wt[idx] = f2bf(W[(size_t)k * CCH + n] * sinv[k >> 4]);
}

// ------ K=128 GEMM, full A-tile resident, NT column tiles per block. ------
// OUTMODE: 1 = bf16 out (Nc = NT*128), 2 = qkv-packed 512B rows (NT=3).
// LNA: A source is fp32 x with LayerNorm fused into the A-stage.
template <int NT, int OUTMODE, bool LNA, bool RELU>
__global__ __launch_bounds__(256) void k_gemm128(const void* __restrict__ Ain,
                                                 const unsigned short* __restrict__ Bt,
                                                 const float* __restrict__ bias,
                                                 const float* __restrict__ lng,
                                                 const float* __restrict__ lnb,
                                                 void* __restrict__ outp) {
  __shared__ unsigned short As[64 * 128];   // 16 KB
  __shared__ unsigned short Bs[128 * 128];  // 32 KB
  const int tid  = threadIdx.x;
  const int row0 = blockIdx.x * 64;
  const int l    = tid & 63;
  const int w    = tid >> 6;
  const int wr   = w >> 1;
  const int wc   = w & 1;

  // ---- stage A (once) ----
  if (LNA) {
    // row r = tid>>2, quarter qt = tid&3 -> cols qt*32..+31 (8 float4)
    const float* x = (const float*)Ain;
    int r = tid >> 2, qt = tid & 3;
    const float4* xr = (const float4*)(x + (size_t)(row0 + r) * 128 + qt * 32);
    float4 xv[8];
    float s = 0.f, ss = 0.f;
    #pragma unroll
    for (int i = 0; i < 8; i++) {
      xv[i] = xr[i];
      s  += xv[i].x + xv[i].y + xv[i].z + xv[i].w;
      ss += xv[i].x * xv[i].x + xv[i].y * xv[i].y + xv[i].z * xv[i].z + xv[i].w * xv[i].w;
    }
    s += __shfl_xor(s, 1); ss += __shfl_xor(ss, 1);
    s += __shfl_xor(s, 2); ss += __shfl_xor(ss, 2);
    float mean = s * (1.f / 128.f);
    float var  = ss * (1.f / 128.f) - mean * mean;
    float rstd = rsqrtf(var + 1e-5f);
    #pragma unroll
    for (int i = 0; i < 8; i += 2) {
      int c0 = qt * 32 + i * 4;
      float va[8] = {xv[i].x, xv[i].y, xv[i].z, xv[i].w,
                     xv[i+1].x, xv[i+1].y, xv[i+1].z, xv[i+1].w};
      unsigned short tmp[8];
      #pragma unroll
      for (int u = 0; u < 8; u++)
        tmp[u] = f2bf((va[u] - mean) * rstd * lng[c0 + u] + lnb[c0 + u]);
      int slot = c0 >> 3;
      *(uint4*)(As + r * 128 + ((slot ^ (r & 7)) * 8)) = *(uint4*)tmp;
    }
  } else {
    const unsigned short* A = (const unsigned short*)Ain;
    #pragma unroll
    for (int it = 0; it < 4; it++) {
      int idx = it * 256 + tid;
      int r = idx >> 4, sl = idx & 15;
      uint4 vv = *(const uint4*)(A + (size_t)(row0 + r) * 128 + sl * 8);
      *(uint4*)(As + r * 128 + ((sl ^ (r & 7)) * 8)) = vv;
    }
  }

  // ---- column tiles ----
  #pragma unroll
  for (int t = 0; t < NT; t++) {
    __syncthreads();
    #pragma unroll
    for (int it = 0; it < 8; it++) {
      int idx = it * 256 + tid;
      int n = idx >> 4, sl = idx & 15;
      uint4 vv = *(const uint4*)(Bt + (size_t)(t * 128 + n) * 128 + sl * 8);
      *(uint4*)(Bs + n * 128 + ((sl ^ (n & 7)) * 8)) = vv;
    }
    __syncthreads();

    f32x4 acc[2][4] = {};
    #pragma unroll
    for (int kk = 0; kk < 4; kk++) {
      int sb = kk * 4 + (l >> 4);
      bf16x8 af[2], bfr[4];
      #pragma unroll
      for (int mi = 0; mi < 2; mi++) {
        int r = wr * 32 + mi * 16 + (l & 15);
        af[mi] = *(const bf16x8*)(As + r * 128 + ((sb ^ (r & 7)) * 8));
      }
      #pragma unroll
      for (int ni = 0; ni < 4; ni++) {
        int n = wc * 64 + ni * 16 + (l & 15);
        bfr[ni] = *(const bf16x8*)(Bs + n * 128 + ((sb ^ (n & 7)) * 8));
      }
      #pragma unroll
      for (int mi = 0; mi < 2; mi++)
        #pragma unroll
        for (int ni = 0; ni < 4; ni++)
          acc[mi][ni] = __builtin_amdgcn_mfma_f32_16x16x32_bf16(af[mi], bfr[ni], acc[mi][ni], 0, 0, 0);
    }

    #pragma unroll
    for (int mi = 0; mi < 2; mi++) {
      #pragma unroll
      for (int p = 0; p < 4; p++) {
        int r = row0 + wr * 32 + mi * 16 + (l >> 4) * 4 + p;
        #pragma unroll
        for (int ni = 0; ni < 4; ni++) {
          int cc = wc * 64 + ni * 16 + (l & 15);
          int c  = t * 128 + cc;
          float val = acc[mi][ni][p] + bias[c];
          if (RELU) val = fmaxf(val, 0.f);
          if (OUTMODE == 1) {
            ((unsigned short*)outp)[(size_t)r * (NT * 128) + c] = f2bf(val);
          } else {
            char* rowb = (char*)outp + (size_t)r * 512;
            if (t == 0)      *(unsigned short*)(rowb + cc * 2) = f2bf(val);
            else if (t == 1) *(unsigned char*)(rowb + 256 + cc) = f2fp8(val);
            else             *(unsigned char*)(rowb + 384 + cc) = f2fp8(val);
          }
        }
      }
    }
  }
}

// ------ Generic MFMA GEMM (kc loop). Used for Wo(+LN2) and FFN2. ----------
// MODE: 0=f32 out, 3=Wo+LN2 fused (outp=x1 bf16, outp2=xn2 bf16, res fp32)
// RESMODE: 0=none, 1=fp32, 2=bf16
template <bool RELU, int RESMODE, int MODE>
__global__ __launch_bounds__(256) void k_mgemm(const unsigned short* __restrict__ A,
                                               const unsigned short* __restrict__ Bt,
                                               const float* __restrict__ bias,
                                               const void* __restrict__ res,
                                               void* __restrict__ outp,
                                               int K, int Nc,
                                               const float* __restrict__ lng,
                                               const float* __restrict__ lnb,
                                               void* __restrict__ outp2) {
  __shared__ unsigned short As[64 * 64];
  __shared__ unsigned short Bs[128 * 64];
  const int tid  = threadIdx.x;
  const int row0 = blockIdx.x * 64;
  const int c0   = blockIdx.y * 128;
  const int l    = tid & 63;
  const int w    = tid >> 6;
  const int wr   = w >> 1;
  const int wc   = w & 1;

  f32x4 acc[2][4] = {};

  for (int kc = 0; kc < K; kc += 64) {
    __syncthreads();
    #pragma unroll
    for (int it = 0; it < 2; it++) {
      int idx = it * 256 + tid;
      int r = idx >> 3, s = idx & 7;
      uint4 vv = *(const uint4*)(A + (size_t)(row0 + r) * K + kc + s * 8);
      *(uint4*)(As + r * 64 + ((s ^ (r & 7)) * 8)) = vv;
    }
    #pragma unroll
    for (int it = 0; it < 4; it++) {
      int idx = it * 256 + tid;
      int n = idx >> 3, s = idx & 7;
      uint4 vv = *(const uint4*)(Bt + (size_t)(c0 + n) * K + kc + s * 8);
      *(uint4*)(Bs + n * 64 + ((s ^ (n & 7)) * 8)) = vv;
    }
    __syncthreads();
    #pragma unroll
    for (int kk = 0; kk < 2; kk++) {
      int sb = kk * 4 + (l >> 4);
      bf16x8 af[2], bfr[4];
      #pragma unroll
      for (int mi = 0; mi < 2; mi++) {
        int r = wr * 32 + mi * 16 + (l & 15);
        af[mi] = *(const bf16x8*)(As + r * 64 + ((sb ^ (r & 7)) * 8));
      }
      #pragma unroll
      for (int ni = 0; ni < 4; ni++) {
        int n = wc * 64 + ni * 16 + (l & 15);
        bfr[ni] = *(const bf16x8*)(Bs + n * 64 + ((sb ^ (n & 7)) * 8));
      }
      #pragma unroll
      for (int mi = 0; mi < 2; mi++)
        #pragma unroll
        for (int ni = 0; ni < 4; ni++)
          acc[mi][ni] = __builtin_amdgcn_mfma_f32_16x16x32_bf16(af[mi], bfr[ni], acc[mi][ni], 0, 0, 0);
    }
  }

  if constexpr (MODE == 3) {
    __shared__ float lnS[64][2], lnSS[64][2], gS[128], bS[128];
    if (tid < 128) { gS[tid] = lng[tid]; bS[tid] = lnb[tid]; }
    #pragma unroll
    for (int mi = 0; mi < 2; mi++) {
      #pragma unroll
      for (int p = 0; p < 4; p++) {
        int lr = wr * 32 + mi * 16 + (l >> 4) * 4 + p;
        int r  = row0 + lr;
        float s = 0.f, ss = 0.f;
        #pragma unroll
        for (int ni = 0; ni < 4; ni++) {
          int c = wc * 64 + ni * 16 + (l & 15);
          float val = acc[mi][ni][p] + bias[c] + ((const float*)res)[(size_t)r * 128 + c];
          acc[mi][ni][p] = val;
          s += val; ss += val * val;
        }
        #pragma unroll
        for (int d = 1; d < 16; d <<= 1) { s += __shfl_xor(s, d); ss += __shfl_xor(ss, d); }
        if ((l & 15) == 0) { lnS[lr][wc] = s; lnSS[lr][wc] = ss; }
      }
    }
    __syncthreads();
    #pragma unroll
    for (int mi = 0; mi < 2; mi++) {
      #pragma unroll
      for (int p = 0; p < 4; p++) {
        int lr = wr * 32 + mi * 16 + (l >> 4) * 4 + p;
        int r  = row0 + lr;
        float m   = (lnS[lr][0] + lnS[lr][1]) * (1.f / 128.f);
        float var = (lnSS[lr][0] + lnSS[lr][1]) * (1.f / 128.f) - m * m;
        float rstd = rsqrtf(var + 1e-5f);
        #pragma unroll
        for (int ni = 0; ni < 4; ni++) {
          int c = wc * 64 + ni * 16 + (l & 15);
          float val = acc[mi][ni][p];
          ((unsigned short*)outp)[(size_t)r * 128 + c]  = f2bf(val);
          ((unsigned short*)outp2)[(size_t)r * 128 + c] = f2bf((val - m) * rstd * gS[c] + bS[c]);
        }
      }
    }
  } else {
    #pragma unroll
    for (int mi = 0; mi < 2; mi++) {
      #pragma unroll
      for (int p = 0; p < 4; p++) {
        int r = row0 + wr * 32 + mi * 16 + (l >> 4) * 4 + p;
        #pragma unroll
        for (int ni = 0; ni < 4; ni++) {
          int c = c0 + wc * 64 + ni * 16 + (l & 15);
          float val = acc[mi][ni][p] + bias[c];
          if (RESMODE == 1) val += ((const float*)res)[(size_t)r * Nc + c];
          if (RESMODE == 2) val += bfs(((const unsigned short*)res)[(size_t)r * Nc + c]);
          if (RELU) val = fmaxf(val, 0.f);
          ((float*)outp)[(size_t)r * Nc + c] = val;
        }
      }
    }
  }
}

// ------- CSR build: histogram+rank -> 3-stage scan -> atomic-free scatter --
__global__ __launch_bounds__(256) void k_histrank(const int* __restrict__ ei,
                                                  int* __restrict__ deg,
                                                  int* __restrict__ rank) {
  int e = blockIdx.x * 256 + threadIdx.x;
  if (e >= NEDGE) return;
  rank[e] = atomicAdd(&deg[ei[NEDGE + e]], 1);
}

__global__ __launch_bounds__(256) void k_scan3a(const int* __restrict__ deg,
                                                int* __restrict__ bsum) {
  int i = blockIdx.x * 256 + threadIdx.x;
  int d = (i < NNODES) ? deg[i] : 0;
  #pragma unroll
  for (int s = 1; s < 64; s <<= 1) d += __shfl_xor(d, s);
  __shared__ int ws4[4];
  if ((threadIdx.x & 63) == 0) ws4[threadIdx.x >> 6] = d;
  __syncthreads();
  if (threadIdx.x == 0) bsum[blockIdx.x] = ws4[0] + ws4[1] + ws4[2] + ws4[3];
}

__global__ __launch_bounds__(256) void k_scan3b(const int* __restrict__ bsum,
                                                int* __restrict__ bpre) {
  int t = threadIdx.x;
  int d = (t < NBLK) ? bsum[t] : 0;
  int lane = t & 63, wv = t >> 6;
  int incl = d;
  #pragma unroll
  for (int s = 1; s < 64; s <<= 1) { int o = __shfl_up(incl, s); if (lane >= s) incl += o; }
  __shared__ int wsum[4];
  if (lane == 63) wsum[wv] = incl;
  __syncthreads();
  int base = 0;
  for (int w2 = 0; w2 < wv; w2++) base += wsum[w2];
  if (t < NBLK) bpre[t] = base + incl - d;
}

__global__ __launch_bounds__(256) void k_scan3c(const int* __restrict__ deg,
                                                const int* __restrict__ bpre,
                                                int* __restrict__ off) {
  int t = threadIdx.x;
  int i = blockIdx.x * 256 + t;
  int d = (i < NNODES) ? deg[i] : 0;
  int lane = t & 63, wv = t >> 6;
  int incl = d;
  #pragma unroll
  for (int s = 1; s < 64; s <<= 1) { int o = __shfl_up(incl, s); if (lane >= s) incl += o; }
  __shared__ int wsum[4];
  if (lane == 63) wsum[wv] = incl;
  __syncthreads();
  int base = bpre[blockIdx.x];
  for (int w2 = 0; w2 < wv; w2++) base += wsum[w2];
  int ex = base + incl - d;
  if (i < NNODES) off[i] = ex;
  if (i == 0) off[NNODES] = NEDGE;
}

__global__ __launch_bounds__(256) void k_scatter(const int* __restrict__ ei,
                                                 const int* __restrict__ off,
                                                 const int* __restrict__ rank,
                                                 int* __restrict__ srcs) {
  int e = blockIdx.x * 256 + threadIdx.x;
  if (e >= NEDGE) return;
  srcs[off[ei[NEDGE + e]] + rank[e]] = ei[e];
}

// ------- Fused scores + aggregation: 1 wave/node, 1 lane = 1 (edge,head) ---
// qkv row (512B): [0,256) q bf16 x128; [256,384) k fp8 x128; [384,512) v fp8.
// 2-stage pipeline: next 8-edge block's k/v loads issued before computing
// the current block (indices clamped to valid edges -> no garbage/NaN).
__global__ __launch_bounds__(256) void k_fused(const unsigned char* __restrict__ qkv,
                                               const int* __restrict__ off,
                                               const int* __restrict__ srcs,
                                               unsigned* __restrict__ U,
                                               float* __restrict__ hpart) {
  const int wave = threadIdx.x >> 6;
  const int lane = threadIdx.x & 63;
  const int n  = blockIdx.x * 4 + wave;
  const int g  = lane >> 3;   // edge slot 0..7
  const int c8 = lane & 7;    // head; channels c8*16 .. +15

  const uint4* qp = (const uint4*)(qkv + (size_t)n * 512 + c8 * 32);
  uint4 qa = qp[0], qb = qp[1];
  float qf[16];
  qf[0]=bflo(qa.x);  qf[1]=bfhi(qa.x);  qf[2]=bflo(qa.y);  qf[3]=bfhi(qa.y);
  qf[4]=bflo(qa.z);  qf[5]=bfhi(qa.z);  qf[6]=bflo(qa.w);  qf[7]=bfhi(qa.w);
  qf[8]=bflo(qb.x);  qf[9]=bfhi(qb.x);  qf[10]=bflo(qb.y); qf[11]=bfhi(qb.y);
  qf[12]=bflo(qb.z); qf[13]=bfhi(qb.z); qf[14]=bflo(qb.w); qf[15]=bfhi(qb.w);

  float acc[16];
  #pragma unroll
  for (int i = 0; i < 16; i++) acc[i] = 0.f;
  float lsum = 0.f;

  const int i0 = off[n], i1 = off[n + 1];
  if (i1 > i0) {
    int j0 = i0 + g; if (j0 >= i1) j0 = i1 - 1;
    int src = srcs[j0];
    const uint4* kp = (const uint4*)(qkv + (size_t)src * 512 + 256 + c8 * 16);
    uint4 kw = kp[0], vw = kp[8];
    for (int jb = i0; jb < i1; jb += 8) {
      uint4 kc = kw, vc = vw;
      bool valid = jb + g < i1;
      int jn = jb + 8;
      if (jn < i1) {
        int j2 = jn + g; if (j2 >= i1) j2 = i1 - 1;
        int srcn = srcs[j2];
        const uint4* kpn = (const uint4*)(qkv + (size_t)srcn * 512 + 256 + c8 * 16);
        kw = kpn[0]; vw = kpn[8];
      }
      float kf[16], vf[16];
      fp8x4d(kc.x, kf + 0); fp8x4d(kc.y, kf + 4); fp8x4d(kc.z, kf + 8); fp8x4d(kc.w, kf + 12);
      fp8x4d(vc.x, vf + 0); fp8x4d(vc.y, vf + 4); fp8x4d(vc.z, vf + 8); fp8x4d(vc.w, vf + 12);
      float p = 0.f;
      #pragma unroll
      for (int i = 0; i < 16; i++) p += qf[i] * kf[i];
      float w = valid ? __expf(p * 0.25f) : 0.f;
      lsum += w;
      #pragma unroll
      for (int i = 0; i < 16; i++) acc[i] += w * vf[i];
    }
  }

  #pragma unroll
  for (int d = 8; d < 64; d <<= 1) {
    #pragma unroll
    for (int i = 0; i < 16; i++) acc[i] += __shfl_xor(acc[i], d);
    lsum += __shfl_xor(lsum, d);
  }

  __shared__ float wsum[4][8];
  if (lane < 8) {
    wsum[wave][c8] = lsum;
    unsigned o[8];
    #pragma unroll
    for (int i = 0; i < 8; i++)
      o[i] = ((unsigned)f2bf(acc[2 * i + 1]) << 16) | f2bf(acc[2 * i]);
    uint4* up = (uint4*)(U + (size_t)n * 64 + c8 * 8);
    up[0] = make_uint4(o[0], o[1], o[2], o[3]);
    up[1] = make_uint4(o[4], o[5], o[6], o[7]);
  }
  __syncthreads();
  if (threadIdx.x < 8) {
    hpart[blockIdx.x * 8 + threadIdx.x] =
        wsum[0][threadIdx.x] + wsum[1][threadIdx.x] + wsum[2][threadIdx.x] + wsum[3][threadIdx.x];
  }
}

// ---- Stage-1 denominator reduce: hpart[10000][8] -> dpart[40][8] ----------
__global__ __launch_bounds__(256) void k_reduce_part(const float* __restrict__ hpart,
                                                     float* __restrict__ dpart) {
  const int t = threadIdx.x;
  const int h = t & 7;
  const int r0 = blockIdx.x * (FBLK / RBLK);
  float s = 0.f;
  for (int r = r0 + (t >> 3); r < r0 + FBLK / RBLK; r += 32) s += hpart[r * 8 + h];
  #pragma unroll
  for (int d = 8; d < 64; d <<= 1) s += __shfl_xor(s, d);
  __shared__ float ws4[4][8];
  int lane = t & 63, wv = t >> 6;
  if (lane < 8) ws4[wv][lane] = s;
  __syncthreads();
  if (t < 8) dpart[blockIdx.x * 8 + t] = ws4[0][t] + ws4[1][t] + ws4[2][t] + ws4[3][t];
}

extern "C" void kernel_launch(void* const* d_in, const int* in_sizes, int n_in,
                              void* d_out, int out_size, void* d_ws, size_t ws_size,
                              hipStream_t stream) {
  const float* x    = (const float*)d_in[0];
  const int*   ei   = (const int*)d_in[1];
  const float* Wq   = (const float*)d_in[2];
  const float* bq   = (const float*)d_in[3];
  const float* Wk   = (const float*)d_in[4];
  const float* bk   = (const float*)d_in[5];
  const float* Wv   = (const float*)d_in[6];
  const float* bv   = (const float*)d_in[7];
  const float* Wo   = (const float*)d_in[8];
  const float* bo   = (const float*)d_in[9];
  const float* ln1g = (const float*)d_in[10];
  const float* ln1b = (const float*)d_in[11];
  const float* ln2g = (const float*)d_in[12];
  const float* ln2b = (const float*)d_in[13];
  const float* W1   = (const float*)d_in[14];
  const float* b1   = (const float*)d_in[15];
  const float* W2   = (const float*)d_in[16];
  const float* b2   = (const float*)d_in[17];
  float* out = (float*)d_out;

  char* p = (char*)d_ws;
  const size_t NCb = (size_t)NNODES * CCH * 2;                  // 10.24 MB
  unsigned short* xn2  = (unsigned short*)p; p += NCb;          // LN2 out
  unsigned char*  qkvb = (unsigned char*)p;  p += (size_t)NNODES * 512;  // 20.48 MB (ffn1 start)
  unsigned short* agg  = (unsigned short*)p; p += NCb;          // U (ffn1 part)
  p += NCb;                                                     // spare (ffn1 part)
  unsigned short* x1b  = (unsigned short*)p; p += NCb;          // x1 bf16
  int* deg    = (int*)p;                     p += (size_t)NNODES * 4 + 256;
  int* off    = (int*)p;                     p += (size_t)(NNODES + 1) * 4 + 256;
  int* rank   = (int*)p;                     p += (size_t)NEDGE * 4;
  int* srcs   = (int*)p;                     p += (size_t)NEDGE * 4;
  int* bsum   = (int*)p;                     p += 256 * 4;
  int* bpre   = (int*)p;                     p += 256 * 4;
  float* hpart = (float*)p;                  p += (size_t)FBLK * 8 * 4;
  float* dpart = (float*)p;                  p += (size_t)RBLK * 8 * 4 + 256;
  float* bqkv  = (float*)p;                  p += 384 * 4 + 256;
  unsigned short* Wqkvt = (unsigned short*)p; p += (size_t)384 * CCH * 2;
  unsigned short* Wot   = (unsigned short*)p; p += (size_t)CCH * CCH * 2;
  unsigned short* W1t   = (unsigned short*)p; p += (size_t)CCH * 4 * CCH * 2;
  unsigned short* W2t   = (unsigned short*)p; p += (size_t)CCH * 4 * CCH * 2;
  unsigned short* ffn1 = (unsigned short*)qkvb;  // overlays qkvb+agg+spare (40.96 MB)

  dim3 blk(256);
  dim3 gM(NNODES / 64, 1);
  dim3 gE((NEDGE + 255) / 256);

  // 1. weight prep + deg zeroing (one launch)
  k_wprep_all<<<706, blk, 0, stream>>>(Wq, Wk, Wv, W1, W2, bq, bk, bv,
                                       Wqkvt, W1t, W2t, bqkv, deg);

  // 2-6. CSR build: hist+rank -> 3-stage scan -> atomic-free scatter
  k_histrank<<<gE, blk, 0, stream>>>(ei, deg, rank);
  k_scan3a<<<NBLK, blk, 0, stream>>>(deg, bsum);
  k_scan3b<<<1, blk, 0, stream>>>(bsum, bpre);
  k_scan3c<<<NBLK, blk, 0, stream>>>(deg, bpre, off);
  k_scatter<<<gE, blk, 0, stream>>>(ei, off, rank, srcs);

  // 7. LN1 + packed QKV GEMM fused (q bf16 | k fp8 | v fp8, 512B rows)
  k_gemm128<3, 2, true, false><<<gM, blk, 0, stream>>>(x, Wqkvt, bqkv,
                                                       ln1g, ln1b, qkvb);

  // 8-9. fused scores+aggregation, denominator partials
  k_fused<<<FBLK, blk, 0, stream>>>(qkvb, off, srcs, (unsigned*)agg, hpart);
  k_reduce_part<<<RBLK, blk, 0, stream>>>(hpart, dpart);

  // 10. Wo prep (inv inline) -> 11. Wo GEMM + residual-x + LN2 fused
  k_wprep_wo<<<64, blk, 0, stream>>>(Wo, dpart, Wot);
  k_mgemm<false, 1, 3><<<gM, blk, 0, stream>>>(agg, Wot, bo, x, x1b,
                                               CCH, CCH, ln2g, ln2b, xn2);

  // 12. FFN1 (relu, bf16 out, A-tile resident, 4 column tiles)
  k_gemm128<4, 1, false, true><<<gM, blk, 0, stream>>>(xn2, W1t, b1,
                                                       nullptr, nullptr, ffn1);
  // 13. FFN2 (+bf16 residual x1) -> d_out fp32
  k_mgemm<false, 2, 0><<<gM, blk, 0, stream>>>(ffn1, W2t, b2, x1b, out,
                                               4 * CCH, CCH, nullptr, nullptr, nullptr);
}

// Round 12
// 156.486 us; speedup vs baseline: 4.1857x; 1.0315x over previous
//
#include <hip/hip_runtime.h>
#include <math.h>

#define NNODES 40000
#define CCH    128
#define NH     8
#define HD     16
#define NEDGE  640000
#define NBLK   157    // ceil(NNODES/256)
#define FBLK   10000  // k_fused blocks (4 waves each -> 40000 nodes)
#define RBLK   40     // k_reduce_part blocks
#define EBLK   625    // ceil(NEDGE/1024): 4 edges/thread kernels

typedef __attribute__((ext_vector_type(8))) short bf16x8;
typedef __attribute__((ext_vector_type(4))) float f32x4;
typedef __attribute__((ext_vector_type(2))) float f32x2;

__device__ inline unsigned short f2bf(float f) {
  union { float f; unsigned u; } c; c.f = f;
  unsigned r = c.u + 0x7fffu + ((c.u >> 16) & 1u);
  return (unsigned short)(r >> 16);
}
__device__ inline float bfs(unsigned short u) { union { unsigned i; float f; } c; c.i = (unsigned)u << 16; return c.f; }
__device__ inline float bflo(unsigned u) { union { unsigned i; float f; } c; c.i = u << 16; return c.f; }
__device__ inline float bfhi(unsigned u) { union { unsigned i; float f; } c; c.i = u & 0xffff0000u; return c.f; }

// ---- fp8 e4m3 (OCP) helpers ----
__device__ inline unsigned char f2fp8(float v) {
#if __has_builtin(__builtin_amdgcn_cvt_pk_fp8_f32)
  return (unsigned char)(__builtin_amdgcn_cvt_pk_fp8_f32(v, v, 0, false) & 0xff);
#else
  union { float f; unsigned u; } c; c.f = v;
  unsigned s = (c.u >> 24) & 0x80;
  int e = (int)((c.u >> 23) & 0xff) - 127;
  unsigned m = c.u & 0x7fffff;
  if (e > 8) return s | 0x7e;
  if (e >= -6) {
    unsigned q = (m + 0x80000) >> 20; unsigned ee = e + 7;
    if (q == 8) { q = 0; ee++; }
    if (ee > 15) return s | 0x7e;
    return s | (ee << 3) | q;
  }
  if (e < -10) return (unsigned char)s;
  float a = fabsf(v); unsigned q = (unsigned)(a * 512.f + 0.5f); if (q > 7) q = 7;
  return s | q;
#endif
}
__device__ inline void fp8x4d(unsigned w, float* o) {
#if __has_builtin(__builtin_amdgcn_cvt_pk_f32_fp8)
  f32x2 lo = __builtin_amdgcn_cvt_pk_f32_fp8((int)w, false);
  f32x2 hi = __builtin_amdgcn_cvt_pk_f32_fp8((int)w, true);
  o[0] = lo[0]; o[1] = lo[1]; o[2] = hi[0]; o[3] = hi[1];
#else
  #pragma unroll
  for (int i = 0; i < 4; i++) {
    unsigned b = (w >> (8 * i)) & 0xff;
    unsigned s = b >> 7, e = (b >> 3) & 15, m = b & 7;
    float v;
    if (e) { union { unsigned u; float f; } c; c.u = ((e + 120) << 23) | (m << 20); v = c.f; }
    else v = m * (1.f / 512.f);
    o[i] = s ? -v : v;
  }
#endif
}

// -------- Combined weight prep (+deg zeroing): Wqkvt, W1t, W2t, bqkv ------
__global__ __launch_bounds__(256) void k_wprep_all(const float* __restrict__ Wq,
                                                   const float* __restrict__ Wk,
                                                   const float* __restrict__ Wv,
                                                   const float* __restrict__ W1,
                                                   const float* __restrict__ W2,
                                                   const float* __restrict__ bq,
                                                   const float* __restrict__ bk,
                                                   const float* __restrict__ bv,
                                                   unsigned short* __restrict__ Wqkvt,
                                                   unsigned short* __restrict__ W1t,
                                                   unsigned short* __restrict__ W2t,
                                                   float* __restrict__ bqkv,
                                                   int* __restrict__ deg) {
  int g0 = blockIdx.x * 256 + threadIdx.x;
  if (g0 < NNODES) deg[g0] = 0;
  int idx = g0;
  if (idx < 16384) { int n = idx >> 7, k = idx & 127; Wqkvt[idx] = f2bf(Wq[(size_t)k * 128 + n]); return; }
  idx -= 16384;
  if (idx < 16384) { int n = idx >> 7, k = idx & 127; Wqkvt[16384 + (n << 7) + k] = f2bf(Wk[(size_t)k * 128 + n]); return; }
  idx -= 16384;
  if (idx < 16384) { int n = idx >> 7, k = idx & 127; Wqkvt[32768 + (n << 7) + k] = f2bf(Wv[(size_t)k * 128 + n]); return; }
  idx -= 16384;
  if (idx < 65536) { int n = idx >> 7, k = idx & 127; W1t[idx] = f2bf(W1[(size_t)k * 512 + n]); return; }
  idx -= 65536;
  if (idx < 65536) { int n = idx >> 9, k = idx & 511; W2t[idx] = f2bf(W2[(size_t)k * 128 + n]); return; }
  idx -= 65536;
  if (idx < 384) bqkv[idx] = idx < 128 ? bq[idx] : (idx < 256 ? bk[idx - 128] : bv[idx - 256]);
}

// -------- Wo prep: inline inv computation from dpart + row scaling --------
__global__ __launch_bounds__(256) void k_wprep_wo(const float* __restrict__ W,
                                                  const float* __restrict__ dpart,
                                                  unsigned short* __restrict__ Wt) {
  __shared__ float sinv[8];
  if (threadIdx.x < 64) {
    int h = threadIdx.x & 7;
    float s = 0.f;
    for (int r = threadIdx.x >> 3; r < RBLK; r += 8) s += dpart[r * 8 + h];
    #pragma unroll
    for (int d = 8; d < 64; d <<= 1) s += __shfl_xor(s, d);
    if (threadIdx.x < 8) sinv[h] = 1.0f / s;
  }
  __syncthreads();
  int idx = blockIdx.x * 256 + threadIdx.x;
  if (idx >= CCH * CCH) return;
  int n = idx >> 7, k = idx & 127;
  Wt[idx] = f2bf(W[(size_t)k * CCH + n] * sinv[k >> 4]);
}

// ------ K=128 GEMM, full A-tile resident, NT column tiles per block. ------
template <int NT, int OUTMODE, bool LNA, bool RELU>
__global__ __launch_bounds__(256) void k_gemm128(const void* __restrict__ Ain,
                                                 const unsigned short* __restrict__ Bt,
                                                 const float* __restrict__ bias,
                                                 const float* __restrict__ lng,
                                                 const float* __restrict__ lnb,
                                                 void* __restrict__ outp) {
  __shared__ unsigned short As[64 * 128];   // 16 KB
  __shared__ unsigned short Bs[128 * 128];  // 32 KB
  const int tid  = threadIdx.x;
  const int row0 = blockIdx.x * 64;
  const int l    = tid & 63;
  const int w    = tid >> 6;
  const int wr   = w >> 1;
  const int wc   = w & 1;

  if (LNA) {
    const float* x = (const float*)Ain;
    int r = tid >> 2, qt = tid & 3;
    const float4* xr = (const float4*)(x + (size_t)(row0 + r) * 128 + qt * 32);
    float4 xv[8];
    float s = 0.f, ss = 0.f;
    #pragma unroll
    for (int i = 0; i < 8; i++) {
      xv[i] = xr[i];
      s  += xv[i].x + xv[i].y + xv[i].z + xv[i].w;
      ss += xv[i].x * xv[i].x + xv[i].y * xv[i].y + xv[i].z * xv[i].z + xv[i].w * xv[i].w;
    }
    s += __shfl_xor(s, 1); ss += __shfl_xor(ss, 1);
    s += __shfl_xor(s, 2); ss += __shfl_xor(ss, 2);
    float mean = s * (1.f / 128.f);
    float var  = ss * (1.f / 128.f) - mean * mean;
    float rstd = rsqrtf(var + 1e-5f);
    #pragma unroll
    for (int i = 0; i < 8; i += 2) {
      int c0 = qt * 32 + i * 4;
      float va[8] = {xv[i].x, xv[i].y, xv[i].z, xv[i].w,
                     xv[i+1].x, xv[i+1].y, xv[i+1].z, xv[i+1].w};
      unsigned short tmp[8];
      #pragma unroll
      for (int u = 0; u < 8; u++)
        tmp[u] = f2bf((va[u] - mean) * rstd * lng[c0 + u] + lnb[c0 + u]);
      int slot = c0 >> 3;
      *(uint4*)(As + r * 128 + ((slot ^ (r & 7)) * 8)) = *(uint4*)tmp;
    }
  } else {
    const unsigned short* A = (const unsigned short*)Ain;
    #pragma unroll
    for (int it = 0; it < 4; it++) {
      int idx = it * 256 + tid;
      int r = idx >> 4, sl = idx & 15;
      uint4 vv = *(const uint4*)(A + (size_t)(row0 + r) * 128 + sl * 8);
      *(uint4*)(As + r * 128 + ((sl ^ (r & 7)) * 8)) = vv;
    }
  }

  #pragma unroll
  for (int t = 0; t < NT; t++) {
    __syncthreads();
    #pragma unroll
    for (int it = 0; it < 8; it++) {
      int idx = it * 256 + tid;
      int n = idx >> 4, sl = idx & 15;
      uint4 vv = *(const uint4*)(Bt + (size_t)(t * 128 + n) * 128 + sl * 8);
      *(uint4*)(Bs + n * 128 + ((sl ^ (n & 7)) * 8)) = vv;
    }
    __syncthreads();

    f32x4 acc[2][4] = {};
    #pragma unroll
    for (int kk = 0; kk < 4; kk++) {
      int sb = kk * 4 + (l >> 4);
      bf16x8 af[2], bfr[4];
      #pragma unroll
      for (int mi = 0; mi < 2; mi++) {
        int r = wr * 32 + mi * 16 + (l & 15);
        af[mi] = *(const bf16x8*)(As + r * 128 + ((sb ^ (r & 7)) * 8));
      }
      #pragma unroll
      for (int ni = 0; ni < 4; ni++) {
        int n = wc * 64 + ni * 16 + (l & 15);
        bfr[ni] = *(const bf16x8*)(Bs + n * 128 + ((sb ^ (n & 7)) * 8));
      }
      #pragma unroll
      for (int mi = 0; mi < 2; mi++)
        #pragma unroll
        for (int ni = 0; ni < 4; ni++)
          acc[mi][ni] = __builtin_amdgcn_mfma_f32_16x16x32_bf16(af[mi], bfr[ni], acc[mi][ni], 0, 0, 0);
    }

    #pragma unroll
    for (int mi = 0; mi < 2; mi++) {
      #pragma unroll
      for (int p = 0; p < 4; p++) {
        int r = row0 + wr * 32 + mi * 16 + (l >> 4) * 4 + p;
        #pragma unroll
        for (int ni = 0; ni < 4; ni++) {
          int cc = wc * 64 + ni * 16 + (l & 15);
          int c  = t * 128 + cc;
          float val = acc[mi][ni][p] + bias[c];
          if (RELU) val = fmaxf(val, 0.f);
          if (OUTMODE == 1) {
            ((unsigned short*)outp)[(size_t)r * (NT * 128) + c] = f2bf(val);
          } else {
            char* rowb = (char*)outp + (size_t)r * 512;
            if (t == 0)      *(unsigned short*)(rowb + cc * 2) = f2bf(val);
            else if (t == 1) *(unsigned char*)(rowb + 256 + cc) = f2fp8(val);
            else             *(unsigned char*)(rowb + 384 + cc) = f2fp8(val);
          }
        }
      }
    }
  }
}

// ------ Generic MFMA GEMM (kc loop). Used for Wo(+LN2) and FFN2. ----------
template <bool RELU, int RESMODE, int MODE>
__global__ __launch_bounds__(256) void k_mgemm(const unsigned short* __restrict__ A,
                                               const unsigned short* __restrict__ Bt,
                                               const float* __restrict__ bias,
                                               const void* __restrict__ res,
                                               void* __restrict__ outp,
                                               int K, int Nc,
                                               const float* __restrict__ lng,
                                               const float* __restrict__ lnb,
                                               void* __restrict__ outp2) {
  __shared__ unsigned short As[64 * 64];
  __shared__ unsigned short Bs[128 * 64];
  const int tid  = threadIdx.x;
  const int row0 = blockIdx.x * 64;
  const int c0   = blockIdx.y * 128;
  const int l    = tid & 63;
  const int w    = tid >> 6;
  const int wr   = w >> 1;
  const int wc   = w & 1;

  f32x4 acc[2][4] = {};

  for (int kc = 0; kc < K; kc += 64) {
    __syncthreads();
    #pragma unroll
    for (int it = 0; it < 2; it++) {
      int idx = it * 256 + tid;
      int r = idx >> 3, s = idx & 7;
      uint4 vv = *(const uint4*)(A + (size_t)(row0 + r) * K + kc + s * 8);
      *(uint4*)(As + r * 64 + ((s ^ (r & 7)) * 8)) = vv;
    }
    #pragma unroll
    for (int it = 0; it < 4; it++) {
      int idx = it * 256 + tid;
      int n = idx >> 3, s = idx & 7;
      uint4 vv = *(const uint4*)(Bt + (size_t)(c0 + n) * K + kc + s * 8);
      *(uint4*)(Bs + n * 64 + ((s ^ (n & 7)) * 8)) = vv;
    }
    __syncthreads();
    #pragma unroll
    for (int kk = 0; kk < 2; kk++) {
      int sb = kk * 4 + (l >> 4);
      bf16x8 af[2], bfr[4];
      #pragma unroll
      for (int mi = 0; mi < 2; mi++) {
        int r = wr * 32 + mi * 16 + (l & 15);
        af[mi] = *(const bf16x8*)(As + r * 64 + ((sb ^ (r & 7)) * 8));
      }
      #pragma unroll
      for (int ni = 0; ni < 4; ni++) {
        int n = wc * 64 + ni * 16 + (l & 15);
        bfr[ni] = *(const bf16x8*)(Bs + n * 64 + ((sb ^ (n & 7)) * 8));
      }
      #pragma unroll
      for (int mi = 0; mi < 2; mi++)
        #pragma unroll
        for (int ni = 0; ni < 4; ni++)
          acc[mi][ni] = __builtin_amdgcn_mfma_f32_16x16x32_bf16(af[mi], bfr[ni], acc[mi][ni], 0, 0, 0);
    }
  }

  if constexpr (MODE == 3) {
    __shared__ float lnS[64][2], lnSS[64][2], gS[128], bS[128];
    if (tid < 128) { gS[tid] = lng[tid]; bS[tid] = lnb[tid]; }
    #pragma unroll
    for (int mi = 0; mi < 2; mi++) {
      #pragma unroll
      for (int p = 0; p < 4; p++) {
        int lr = wr * 32 + mi * 16 + (l >> 4) * 4 + p;
        int r  = row0 + lr;
        float s = 0.f, ss = 0.f;
        #pragma unroll
        for (int ni = 0; ni < 4; ni++) {
          int c = wc * 64 + ni * 16 + (l & 15);
          float val = acc[mi][ni][p] + bias[c] + ((const float*)res)[(size_t)r * 128 + c];
          acc[mi][ni][p] = val;
          s += val; ss += val * val;
        }
        #pragma unroll
        for (int d = 1; d < 16; d <<= 1) { s += __shfl_xor(s, d); ss += __shfl_xor(ss, d); }
        if ((l & 15) == 0) { lnS[lr][wc] = s; lnSS[lr][wc] = ss; }
      }
    }
    __syncthreads();
    #pragma unroll
    for (int mi = 0; mi < 2; mi++) {
      #pragma unroll
      for (int p = 0; p < 4; p++) {
        int lr = wr * 32 + mi * 16 + (l >> 4) * 4 + p;
        int r  = row0 + lr;
        float m   = (lnS[lr][0] + lnS[lr][1]) * (1.f / 128.f);
        float var = (lnSS[lr][0] + lnSS[lr][1]) * (1.f / 128.f) - m * m;
        float rstd = rsqrtf(var + 1e-5f);
        #pragma unroll
        for (int ni = 0; ni < 4; ni++) {
          int c = wc * 64 + ni * 16 + (l & 15);
          float val = acc[mi][ni][p];
          ((unsigned short*)outp)[(size_t)r * 128 + c]  = f2bf(val);
          ((unsigned short*)outp2)[(size_t)r * 128 + c] = f2bf((val - m) * rstd * gS[c] + bS[c]);
        }
      }
    }
  } else {
    #pragma unroll
    for (int mi = 0; mi < 2; mi++) {
      #pragma unroll
      for (int p = 0; p < 4; p++) {
        int r = row0 + wr * 32 + mi * 16 + (l >> 4) * 4 + p;
        #pragma unroll
        for (int ni = 0; ni < 4; ni++) {
          int c = c0 + wc * 64 + ni * 16 + (l & 15);
          float val = acc[mi][ni][p] + bias[c];
          if (RESMODE == 1) val += ((const float*)res)[(size_t)r * Nc + c];
          if (RESMODE == 2) val += bfs(((const unsigned short*)res)[(size_t)r * Nc + c]);
          if (RELU) val = fmaxf(val, 0.f);
          ((float*)outp)[(size_t)r * Nc + c] = val;
        }
      }
    }
  }
}

// ------- CSR build: hist+rank (4 edges/thread) -> scan -> scatter ----------
__global__ __launch_bounds__(256) void k_histrank(const int* __restrict__ ei,
                                                  int* __restrict__ deg,
                                                  int* __restrict__ rank) {
  int base = blockIdx.x * 1024 + threadIdx.x;
  #pragma unroll
  for (int u = 0; u < 4; u++) {
    int e = base + u * 256;
    if (e < NEDGE) rank[e] = atomicAdd(&deg[ei[NEDGE + e]], 1);
  }
}

__global__ __launch_bounds__(256) void k_scan3a(const int* __restrict__ deg,
                                                int* __restrict__ bsum) {
  int i = blockIdx.x * 256 + threadIdx.x;
  int d = (i < NNODES) ? deg[i] : 0;
  #pragma unroll
  for (int s = 1; s < 64; s <<= 1) d += __shfl_xor(d, s);
  __shared__ int ws4[4];
  if ((threadIdx.x & 63) == 0) ws4[threadIdx.x >> 6] = d;
  __syncthreads();
  if (threadIdx.x == 0) bsum[blockIdx.x] = ws4[0] + ws4[1] + ws4[2] + ws4[3];
}

// scan3c with fused block-prefix: base = sum_{j<blockIdx.x} bsum[j]
__global__ __launch_bounds__(256) void k_scan3c(const int* __restrict__ deg,
                                                const int* __restrict__ bsum,
                                                int* __restrict__ off) {
  const int t = threadIdx.x;
  __shared__ int ws4[4];
  __shared__ int sbase;
  {
    int lim = blockIdx.x < NBLK ? blockIdx.x : NBLK;
    int v = (t < lim) ? bsum[t] : 0;
    #pragma unroll
    for (int s = 1; s < 64; s <<= 1) v += __shfl_xor(v, s);
    if ((t & 63) == 0) ws4[t >> 6] = v;
    __syncthreads();
    if (t == 0) sbase = ws4[0] + ws4[1] + ws4[2] + ws4[3];
    __syncthreads();
  }
  int i = blockIdx.x * 256 + t;
  int d = (i < NNODES) ? deg[i] : 0;
  int lane = t & 63, wv = t >> 6;
  int incl = d;
  #pragma unroll
  for (int s = 1; s < 64; s <<= 1) { int o = __shfl_up(incl, s); if (lane >= s) incl += o; }
  __syncthreads();
  if (lane == 63) ws4[wv] = incl;
  __syncthreads();
  int base = sbase;
  for (int w2 = 0; w2 < wv; w2++) base += ws4[w2];
  int ex = base + incl - d;
  if (i < NNODES) off[i] = ex;
  if (i == 0) off[NNODES] = NEDGE;
}

__global__ __launch_bounds__(256) void k_scatter(const int* __restrict__ ei,
                                                 const int* __restrict__ off,
                                                 const int* __restrict__ rank,
                                                 int* __restrict__ srcs) {
  int base = blockIdx.x * 1024 + threadIdx.x;
  #pragma unroll
  for (int u = 0; u < 4; u++) {
    int e = base + u * 256;
    if (e < NEDGE) srcs[off[ei[NEDGE + e]] + rank[e]] = ei[e];
  }
}

// ------- Fused scores + aggregation: 1 wave/node, 1 lane = 1 (edge,head) ---
// qkv row (512B): [0,256) q bf16 x128; [256,384) k fp8 x128; [384,512) v fp8.
// 3-deep decoupled pipeline: srcs prefetched one full block ahead of the k/v
// loads, which are one block ahead of compute.
__global__ __launch_bounds__(256) void k_fused(const unsigned char* __restrict__ qkv,
                                               const int* __restrict__ off,
                                               const int* __restrict__ srcs,
                                               unsigned* __restrict__ U,
                                               float* __restrict__ hpart) {
  const int wave = threadIdx.x >> 6;
  const int lane = threadIdx.x & 63;
  const int n  = blockIdx.x * 4 + wave;
  const int g  = lane >> 3;   // edge slot 0..7
  const int c8 = lane & 7;    // head; channels c8*16 .. +15

  const uint4* qp = (const uint4*)(qkv + (size_t)n * 512 + c8 * 32);
  uint4 qa = qp[0], qb = qp[1];
  float qf[16];
  qf[0]=bflo(qa.x);  qf[1]=bfhi(qa.x);  qf[2]=bflo(qa.y);  qf[3]=bfhi(qa.y);
  qf[4]=bflo(qa.z);  qf[5]=bfhi(qa.z);  qf[6]=bflo(qa.w);  qf[7]=bfhi(qa.w);
  qf[8]=bflo(qb.x);  qf[9]=bfhi(qb.x);  qf[10]=bflo(qb.y); qf[11]=bfhi(qb.y);
  qf[12]=bflo(qb.z); qf[13]=bfhi(qb.z); qf[14]=bflo(qb.w); qf[15]=bfhi(qb.w);

  float acc[16];
  #pragma unroll
  for (int i = 0; i < 16; i++) acc[i] = 0.f;
  float lsum = 0.f;

  const int i0 = off[n], i1 = off[n + 1];
  if (i1 > i0) {
    int j0 = i0 + g; if (j0 >= i1) j0 = i1 - 1;
    int sA = srcs[j0];                       // block 0 srcs
    int sB;
    {
      int j1 = i0 + 8 + g;
      if (j1 >= i1) j1 = i1 - 1;
      sB = srcs[j1];                         // block 1 srcs (may dup; fine)
    }
    const uint4* kpA = (const uint4*)(qkv + (size_t)sA * 512 + 256 + c8 * 16);
    uint4 kw = kpA[0], vw = kpA[8];          // block 0 k/v in flight

    for (int jb = i0; jb < i1; jb += 8) {
      uint4 kc = kw, vc = vw;
      bool valid = jb + g < i1;
      // issue next block's k/v from sB (resident), then srcs two blocks out
      if (jb + 8 < i1) {
        const uint4* kpB = (const uint4*)(qkv + (size_t)sB * 512 + 256 + c8 * 16);
        kw = kpB[0]; vw = kpB[8];
      }
      if (jb + 16 < i1) {
        int j2 = jb + 16 + g;
        if (j2 >= i1) j2 = i1 - 1;
        sB = srcs[j2];
      }
      float kf[16], vf[16];
      fp8x4d(kc.x, kf + 0); fp8x4d(kc.y, kf + 4); fp8x4d(kc.z, kf + 8); fp8x4d(kc.w, kf + 12);
      fp8x4d(vc.x, vf + 0); fp8x4d(vc.y, vf + 4); fp8x4d(vc.z, vf + 8); fp8x4d(vc.w, vf + 12);
      float p = 0.f;
      #pragma unroll
      for (int i = 0; i < 16; i++) p += qf[i] * kf[i];
      float w = valid ? __expf(p * 0.25f) : 0.f;
      lsum += w;
      #pragma unroll
      for (int i = 0; i < 16; i++) acc[i] += w * vf[i];
    }
  }

  #pragma unroll
  for (int d = 8; d < 64; d <<= 1) {
    #pragma unroll
    for (int i = 0; i < 16; i++) acc[i] += __shfl_xor(acc[i], d);
    lsum += __shfl_xor(lsum, d);
  }

  __shared__ float wsum[4][8];
  if (lane < 8) {
    wsum[wave][c8] = lsum;
    unsigned o[8];
    #pragma unroll
    for (int i = 0; i < 8; i++)
      o[i] = ((unsigned)f2bf(acc[2 * i + 1]) << 16) | f2bf(acc[2 * i]);
    uint4* up = (uint4*)(U + (size_t)n * 64 + c8 * 8);
    up[0] = make_uint4(o[0], o[1], o[2], o[3]);
    up[1] = make_uint4(o[4], o[5], o[6], o[7]);
  }
  __syncthreads();
  if (threadIdx.x < 8) {
    hpart[blockIdx.x * 8 + threadIdx.x] =
        wsum[0][threadIdx.x] + wsum[1][threadIdx.x] + wsum[2][threadIdx.x] + wsum[3][threadIdx.x];
  }
}

// ---- Stage-1 denominator reduce: hpart[10000][8] -> dpart[40][8] ----------
__global__ __launch_bounds__(256) void k_reduce_part(const float* __restrict__ hpart,
                                                     float* __restrict__ dpart) {
  const int t = threadIdx.x;
  const int h = t & 7;
  const int r0 = blockIdx.x * (FBLK / RBLK);
  float s = 0.f;
  for (int r = r0 + (t >> 3); r < r0 + FBLK / RBLK; r += 32) s += hpart[r * 8 + h];
  #pragma unroll
  for (int d = 8; d < 64; d <<= 1) s += __shfl_xor(s, d);
  __shared__ float ws4[4][8];
  int lane = t & 63, wv = t >> 6;
  if (lane < 8) ws4[wv][lane] = s;
  __syncthreads();
  if (t < 8) dpart[blockIdx.x * 8 + t] = ws4[0][t] + ws4[1][t] + ws4[2][t] + ws4[3][t];
}

extern "C" void kernel_launch(void* const* d_in, const int* in_sizes, int n_in,
                              void* d_out, int out_size, void* d_ws, size_t ws_size,
                              hipStream_t stream) {
  const float* x    = (const float*)d_in[0];
  const int*   ei   = (const int*)d_in[1];
  const float* Wq   = (const float*)d_in[2];
  const float* bq   = (const float*)d_in[3];
  const float* Wk   = (const float*)d_in[4];
  const float* bk   = (const float*)d_in[5];
  const float* Wv   = (const float*)d_in[6];
  const float* bv   = (const float*)d_in[7];
  const float* Wo   = (const float*)d_in[8];
  const float* bo   = (const float*)d_in[9];
  const float* ln1g = (const float*)d_in[10];
  const float* ln1b = (const float*)d_in[11];
  const float* ln2g = (const float*)d_in[12];
  const float* ln2b = (const float*)d_in[13];
  const float* W1   = (const float*)d_in[14];
  const float* b1   = (const float*)d_in[15];
  const float* W2   = (const float*)d_in[16];
  const float* b2   = (const float*)d_in[17];
  float* out = (float*)d_out;

  char* p = (char*)d_ws;
  const size_t NCb = (size_t)NNODES * CCH * 2;                  // 10.24 MB
  unsigned short* xn2  = (unsigned short*)p; p += NCb;          // LN2 out
  unsigned char*  qkvb = (unsigned char*)p;  p += (size_t)NNODES * 512;  // 20.48 MB (ffn1 start)
  unsigned short* agg  = (unsigned short*)p; p += NCb;          // U (ffn1 part)
  p += NCb;                                                     // spare (ffn1 part)
  unsigned short* x1b  = (unsigned short*)p; p += NCb;          // x1 bf16
  int* deg    = (int*)p;                     p += (size_t)NNODES * 4 + 256;
  int* off    = (int*)p;                     p += (size_t)(NNODES + 1) * 4 + 256;
  int* rank   = (int*)p;                     p += (size_t)NEDGE * 4;
  int* srcs   = (int*)p;                     p += (size_t)NEDGE * 4;
  int* bsum   = (int*)p;                     p += 256 * 4;
  float* hpart = (float*)p;                  p += (size_t)FBLK * 8 * 4;
  float* dpart = (float*)p;                  p += (size_t)RBLK * 8 * 4 + 256;
  float* bqkv  = (float*)p;                  p += 384 * 4 + 256;
  unsigned short* Wqkvt = (unsigned short*)p; p += (size_t)384 * CCH * 2;
  unsigned short* Wot   = (unsigned short*)p; p += (size_t)CCH * CCH * 2;
  unsigned short* W1t   = (unsigned short*)p; p += (size_t)CCH * 4 * CCH * 2;
  unsigned short* W2t   = (unsigned short*)p; p += (size_t)CCH * 4 * CCH * 2;
  unsigned short* ffn1 = (unsigned short*)qkvb;  // overlays qkvb+agg+spare (40.96 MB)

  dim3 blk(256);
  dim3 gM(NNODES / 64, 1);

  // 1. weight prep + deg zeroing (one launch)
  k_wprep_all<<<706, blk, 0, stream>>>(Wq, Wk, Wv, W1, W2, bq, bk, bv,
                                       Wqkvt, W1t, W2t, bqkv, deg);

  // 2-5. CSR build: hist+rank (4/thr) -> scan3a -> scan3c(fused prefix) -> scatter (4/thr)
  k_histrank<<<EBLK, blk, 0, stream>>>(ei, deg, rank);
  k_scan3a<<<NBLK, blk, 0, stream>>>(deg, bsum);
  k_scan3c<<<NBLK, blk, 0, stream>>>(deg, bsum, off);
  k_scatter<<<EBLK, blk, 0, stream>>>(ei, off, rank, srcs);

  // 6. LN1 + packed QKV GEMM fused (q bf16 | k fp8 | v fp8, 512B rows)
  k_gemm128<3, 2, true, false><<<gM, blk, 0, stream>>>(x, Wqkvt, bqkv,
                                                       ln1g, ln1b, qkvb);

  // 7-8. fused scores+aggregation, denominator partials
  k_fused<<<FBLK, blk, 0, stream>>>(qkvb, off, srcs, (unsigned*)agg, hpart);
  k_reduce_part<<<RBLK, blk, 0, stream>>>(hpart, dpart);

  // 9. Wo prep (inv inline) -> 10. Wo GEMM + residual-x + LN2 fused
  k_wprep_wo<<<64, blk, 0, stream>>>(Wo, dpart, Wot);
  k_mgemm<false, 1, 3><<<gM, blk, 0, stream>>>(agg, Wot, bo, x, x1b,
                                               CCH, CCH, ln2g, ln2b, xn2);

  // 11. FFN1 (relu, bf16 out, A-tile resident, 4 column tiles)
  k_gemm128<4, 1, false, true><<<gM, blk, 0, stream>>>(xn2, W1t, b1,
                                                       nullptr, nullptr, ffn1);
  // 12. FFN2 (+bf16 residual x1) -> d_out fp32
  k_mgemm<false, 2, 0><<<gM, blk, 0, stream>>>(ffn1, W2t, b2, x1b, out,
                                               4 * CCH, CCH, nullptr, nullptr, nullptr);
}